// Round 3
// baseline (7039.747 us; speedup 1.0000x reference)
//
#include <hip/hip_runtime.h>
#include <hip/hip_bf16.h>

typedef __hip_bfloat16 bf16;

#define D_IN 2048
#define D_OUT 2048
#define DL 512
#define NUM_HEAD 16
#define SEQ 2048
#define HEAD_DIM 128
#define BATCH 2
#define NTOK (BATCH * SEQ) // 4096

// Inputs are float32 per the reference (jnp.float32 everywhere).
// Intermediates stored bf16 in d_ws (40 MiB); f32 accumulation.

__device__ __forceinline__ float ldf(const float* p) { return *p; }
__device__ __forceinline__ float ldf(const bf16* p)  { return __bfloat162float(*p); }
__device__ __forceinline__ void stf(float* p, float v) { *p = v; }
__device__ __forceinline__ void stf(bf16* p, float v)  { *p = __float2bfloat16(v); }

// ---------------------------------------------------------------------------
// Generic tiled GEMM: C[m, col0+n] = A[m,:K] @ W[:K, n] + bias[n]
// A: [M,K] row-major (lda, dtype TA), W: [K,N] row-major f32, C (dtype TC).
// Tile 64x64, block 16x16 threads, 4x4 outputs/thread, K-tile 16, f32 accum.
// ---------------------------------------------------------------------------
template <typename TA, typename TC>
__global__ __launch_bounds__(256) void gemm_bias_kernel(
    const TA* __restrict__ A, int lda,
    const float* __restrict__ W, int ldw,
    const float* __restrict__ bias,
    TC* __restrict__ C, int ldc, int col0,
    int M, int N, int K)
{
    __shared__ float As[64 * 17];  // [row][k], padded
    __shared__ float Bs[16 * 65];  // [k][col], padded
    const int tx = threadIdx.x, ty = threadIdx.y;
    const int tid = ty * 16 + tx;
    const int m0 = blockIdx.y * 64;
    const int n0 = blockIdx.x * 64;

    float acc[4][4] = {};

    for (int k0 = 0; k0 < K; k0 += 16) {
#pragma unroll
        for (int i = 0; i < 4; ++i) {
            int l = tid + 256 * i;
            int r = l >> 4, c = l & 15;
            As[r * 17 + c] = ldf(&A[(m0 + r) * lda + k0 + c]);
        }
#pragma unroll
        for (int i = 0; i < 4; ++i) {
            int l = tid + 256 * i;
            int r = l >> 6, c = l & 63;
            Bs[r * 65 + c] = W[(k0 + r) * ldw + n0 + c];
        }
        __syncthreads();
#pragma unroll
        for (int kk = 0; kk < 16; ++kk) {
            float a[4], b[4];
#pragma unroll
            for (int i = 0; i < 4; ++i) a[i] = As[(ty * 4 + i) * 17 + kk];
#pragma unroll
            for (int j = 0; j < 4; ++j) b[j] = Bs[kk * 65 + tx * 4 + j];
#pragma unroll
            for (int i = 0; i < 4; ++i)
#pragma unroll
                for (int j = 0; j < 4; ++j)
                    acc[i][j] += a[i] * b[j];
        }
        __syncthreads();
    }

#pragma unroll
    for (int i = 0; i < 4; ++i) {
        int row = m0 + ty * 4 + i;
#pragma unroll
        for (int j = 0; j < 4; ++j) {
            int col = n0 + tx * 4 + j;
            stf(&C[row * ldc + col0 + col], acc[i][j] + bias[col]);
        }
    }
}

// ---------------------------------------------------------------------------
// Causal attention, one block per (b, h, q) row; bf16 Q/K/V; writes output
// in place over `query` (block (b,h,q) is the unique reader AND writer of
// query[b*SEQ+q, h*128:(h+1)*128] -> race-free).
// ---------------------------------------------------------------------------
__global__ __launch_bounds__(256) void attn_kernel(
    bf16* __restrict__ query, const bf16* __restrict__ key,
    const bf16* __restrict__ value)
{
    __shared__ float qv[HEAD_DIM];
    __shared__ float sc[SEQ];
    __shared__ float red[256];

    const int q = blockIdx.x;
    const int h = blockIdx.y;
    const int b = blockIdx.z;
    const int tid = threadIdx.x;
    const int base = b * SEQ;
    const int hd0 = h * HEAD_DIM;

    if (tid < HEAD_DIM)
        qv[tid] = __bfloat162float(query[(base + q) * D_OUT + hd0 + tid]);
    __syncthreads();

    const int nk = q + 1;
    const float scale = 0.08838834764831845f; // 1/sqrt(128)

    float lmax = -INFINITY;
    for (int k = tid; k < nk; k += 256) {
        const bf16* kr = key + (base + k) * D_OUT + hd0;
        float s = 0.f;
#pragma unroll 8
        for (int d = 0; d < HEAD_DIM; ++d) s += qv[d] * __bfloat162float(kr[d]);
        s *= scale;
        sc[k] = s;
        lmax = fmaxf(lmax, s);
    }
    red[tid] = lmax;
    __syncthreads();
    for (int off = 128; off > 0; off >>= 1) {
        if (tid < off) red[tid] = fmaxf(red[tid], red[tid + off]);
        __syncthreads();
    }
    const float m = red[0];
    __syncthreads();

    float lsum = 0.f;
    for (int k = tid; k < nk; k += 256) {
        float p = expf(sc[k] - m);
        sc[k] = p;
        lsum += p;
    }
    red[tid] = lsum;
    __syncthreads();
    for (int off = 128; off > 0; off >>= 1) {
        if (tid < off) red[tid] += red[tid + off];
        __syncthreads();
    }
    const float l = red[0];
    __syncthreads();

    const int g = tid >> 7;
    const int d = tid & 127;
    float acc = 0.f;
    for (int k = g; k < nk; k += 2)
        acc += sc[k] * __bfloat162float(value[(base + k) * D_OUT + hd0 + d]);
    red[tid] = acc;
    __syncthreads();
    if (tid < HEAD_DIM) {
        float o = (red[tid] + red[tid + 128]) / l;
        query[(base + q) * D_OUT + hd0 + tid] = __float2bfloat16(o);
    }
}

extern "C" void kernel_launch(void* const* d_in, const int* in_sizes, int n_in,
                              void* d_out, int out_size, void* d_ws, size_t ws_size,
                              hipStream_t stream)
{
    const float* x    = (const float*)d_in[0];
    const float* w_kv = (const float*)d_in[1];
    const float* b_kv = (const float*)d_in[2];
    const float* w_ku = (const float*)d_in[3];
    const float* b_ku = (const float*)d_in[4];
    const float* w_kr = (const float*)d_in[5];
    const float* b_kr = (const float*)d_in[6];
    const float* w_vu = (const float*)d_in[7];
    const float* b_vu = (const float*)d_in[8];
    const float* w_q  = (const float*)d_in[9];
    const float* b_q  = (const float*)d_in[10];
    const float* w_qu = (const float*)d_in[11];
    const float* b_qu = (const float*)d_in[12];
    const float* w_qr = (const float*)d_in[13];
    const float* b_qr = (const float*)d_in[14];
    const float* w_o  = (const float*)d_in[15];
    const float* b_o  = (const float*)d_in[16];
    float* out = (float*)d_out;

    // d_ws carve-up (bf16): 4096*(512+512+2048+2048)*2B = 40 MiB.
    // key (bf16, 16 MiB) lives in d_out scratch (>= 16 MiB under either
    // output-dtype reading); final GEMM reads only query-buffer/w_o and
    // overwrites d_out.
    bf16* ws    = (bf16*)d_ws;
    bf16* ckv   = ws;                      // [4096, 512]
    bf16* qlat  = ckv   + NTOK * DL;       // [4096, 512]
    bf16* query = qlat  + NTOK * DL;       // [4096, 2048] -> attn out in place
    bf16* value = query + NTOK * D_OUT;    // [4096, 2048]
    bf16* key   = (bf16*)d_out;            // [4096, 2048] scratch

    dim3 blk(16, 16);
    auto grid = [](int M, int N) { return dim3(N / 64, M / 64); };

    // ckv = x @ w_kv + b_kv
    gemm_bias_kernel<float, bf16><<<grid(NTOK, DL), blk, 0, stream>>>(
        x, D_IN, w_kv, DL, b_kv, ckv, DL, 0, NTOK, DL, D_IN);
    // q_lat = x @ w_q + b_q
    gemm_bias_kernel<float, bf16><<<grid(NTOK, DL), blk, 0, stream>>>(
        x, D_IN, w_q, DL, b_q, qlat, DL, 0, NTOK, DL, D_IN);
    // key[:, :1024] = ckv @ w_ku + b_ku   (heads 0-7)
    gemm_bias_kernel<bf16, bf16><<<grid(NTOK, D_OUT / 2), blk, 0, stream>>>(
        ckv, DL, w_ku, D_OUT / 2, b_ku, key, D_OUT, 0, NTOK, D_OUT / 2, DL);
    // key[:, 1024:] = x @ w_kr + b_kr     (heads 8-15)
    gemm_bias_kernel<float, bf16><<<grid(NTOK, D_OUT / 2), blk, 0, stream>>>(
        x, D_IN, w_kr, D_OUT / 2, b_kr, key, D_OUT, D_OUT / 2, NTOK, D_OUT / 2, D_IN);
    // query[:, :1024] = q_lat @ w_qu + b_qu
    gemm_bias_kernel<bf16, bf16><<<grid(NTOK, D_OUT / 2), blk, 0, stream>>>(
        qlat, DL, w_qu, D_OUT / 2, b_qu, query, D_OUT, 0, NTOK, D_OUT / 2, DL);
    // query[:, 1024:] = q_lat @ w_qr + b_qr
    gemm_bias_kernel<bf16, bf16><<<grid(NTOK, D_OUT / 2), blk, 0, stream>>>(
        qlat, DL, w_qr, D_OUT / 2, b_qr, query, D_OUT, D_OUT / 2, NTOK, D_OUT / 2, DL);
    // value = ckv @ w_vu + b_vu
    gemm_bias_kernel<bf16, bf16><<<grid(NTOK, D_OUT), blk, 0, stream>>>(
        ckv, DL, w_vu, D_OUT, b_vu, value, D_OUT, 0, NTOK, D_OUT, DL);

    // attention: writes output over query in place
    attn_kernel<<<dim3(SEQ, NUM_HEAD, BATCH), 256, 0, stream>>>(query, key, value);

    // out = attno @ w_o + b_o (f32 output)
    gemm_bias_kernel<bf16, float><<<grid(NTOK, D_OUT), blk, 0, stream>>>(
        query, D_OUT, w_o, D_OUT, b_o, out, D_OUT, 0, NTOK, D_OUT, D_OUT);
}

// Round 4
// 2173.084 us; speedup vs baseline: 3.2395x; 3.2395x over previous
//
#include <hip/hip_runtime.h>
#include <hip/hip_bf16.h>

typedef __hip_bfloat16 bf16;
typedef __bf16 bf16_t;
typedef __bf16 bf16x8 __attribute__((ext_vector_type(8)));
typedef float f32x4 __attribute__((ext_vector_type(4)));

#define D_IN 2048
#define D_OUT 2048
#define DL 512
#define NUM_HEAD 16
#define SEQ 2048
#define HEAD_DIM 128
#define BATCH 2
#define NTOK (BATCH * SEQ) // 4096

__device__ __forceinline__ float ldf(const float* p) { return *p; }
__device__ __forceinline__ float ldf(const bf16* p)  { return __bfloat162float(*p); }
__device__ __forceinline__ void stf(float* p, float v) { *p = v; }
__device__ __forceinline__ void stf(bf16* p, float v)  { *p = __float2bfloat16(v); }

// ---------------------------------------------------------------------------
// Generic tiled GEMM (unchanged from R3): C[m, col0+n] = A @ W + bias
// ---------------------------------------------------------------------------
template <typename TA, typename TC>
__global__ __launch_bounds__(256) void gemm_bias_kernel(
    const TA* __restrict__ A, int lda,
    const float* __restrict__ W, int ldw,
    const float* __restrict__ bias,
    TC* __restrict__ C, int ldc, int col0,
    int M, int N, int K)
{
    __shared__ float As[64 * 17];
    __shared__ float Bs[16 * 65];
    const int tx = threadIdx.x, ty = threadIdx.y;
    const int tid = ty * 16 + tx;
    const int m0 = blockIdx.y * 64;
    const int n0 = blockIdx.x * 64;

    float acc[4][4] = {};

    for (int k0 = 0; k0 < K; k0 += 16) {
#pragma unroll
        for (int i = 0; i < 4; ++i) {
            int l = tid + 256 * i;
            int r = l >> 4, c = l & 15;
            As[r * 17 + c] = ldf(&A[(m0 + r) * lda + k0 + c]);
        }
#pragma unroll
        for (int i = 0; i < 4; ++i) {
            int l = tid + 256 * i;
            int r = l >> 6, c = l & 63;
            Bs[r * 65 + c] = W[(k0 + r) * ldw + n0 + c];
        }
        __syncthreads();
#pragma unroll
        for (int kk = 0; kk < 16; ++kk) {
            float a[4], b[4];
#pragma unroll
            for (int i = 0; i < 4; ++i) a[i] = As[(ty * 4 + i) * 17 + kk];
#pragma unroll
            for (int j = 0; j < 4; ++j) b[j] = Bs[kk * 65 + tx * 4 + j];
#pragma unroll
            for (int i = 0; i < 4; ++i)
#pragma unroll
                for (int j = 0; j < 4; ++j)
                    acc[i][j] += a[i] * b[j];
        }
        __syncthreads();
    }

#pragma unroll
    for (int i = 0; i < 4; ++i) {
        int row = m0 + ty * 4 + i;
#pragma unroll
        for (int j = 0; j < 4; ++j) {
            int col = n0 + tx * 4 + j;
            stf(&C[row * ldc + col0 + col], acc[i][j] + bias[col]);
        }
    }
}

// ---------------------------------------------------------------------------
// MFMA flash attention. Block = 256 threads = 4 waves; Q-tile 64 rows
// (16 rows per wave), K-tile 64; grid (SEQ/64, NUM_HEAD, BATCH).
// mfma_f32_16x16x32_bf16 layouts (m89/m91 verified):
//   A[m][k]: m = lane&15, k = (lane>>4)*8 + j  (8 contiguous k per lane)
//   B[k][n]: n = lane&15, k = (lane>>4)*8 + j
//   C/D:     col = lane&15, row = (lane>>4)*4 + reg
// Q fragments stay in registers all kernel; K staged in LDS (stride 136);
// V staged transposed (stride 72); P round-trips wave-private LDS (m120).
// Output written in place over `query` (block is unique reader+writer of
// its rows/head slice).
// ---------------------------------------------------------------------------
#define KS_LD 136
#define VT_LD 72
#define P_LD  72

__global__ __launch_bounds__(256) void attn_mfma_kernel(
    bf16_t* __restrict__ Qg, const bf16_t* __restrict__ Kg,
    const bf16_t* __restrict__ Vg)
{
    __shared__ __align__(16) bf16_t Ks[64 * KS_LD];     // 17408 B
    __shared__ __align__(16) bf16_t Vt[128 * VT_LD];    // 18432 B
    __shared__ __align__(16) bf16_t Pls[4 * 16 * P_LD]; //  9216 B

    const int tid  = threadIdx.x;
    const int wave = tid >> 6;
    const int lane = tid & 63;
    const int quad = lane >> 4;
    const int l16  = lane & 15;

    const int q0   = blockIdx.x * 64;
    const int h    = blockIdx.y;
    const int b    = blockIdx.z;
    const int base = b * SEQ;
    const int hd0  = h * HEAD_DIM;

    const float scale = 0.08838834764831845f; // 1/sqrt(128)

    // Q fragments: rows q0 + wave*16 + l16, all 128 dims (4 k-blocks of 32)
    bf16x8 qfrag[4];
    {
        const bf16_t* qrow = Qg + (size_t)(base + q0 + wave * 16 + l16) * D_OUT + hd0;
#pragma unroll
        for (int kb = 0; kb < 4; ++kb)
            qfrag[kb] = *(const bf16x8*)(qrow + kb * 32 + quad * 8);
    }

    f32x4 o[8];
#pragma unroll
    for (int ob = 0; ob < 8; ++ob) o[ob] = (f32x4){0.f, 0.f, 0.f, 0.f};
    float m_i[4] = {-INFINITY, -INFINITY, -INFINITY, -INFINITY};
    float l_i[4] = {0.f, 0.f, 0.f, 0.f};

    const int ntiles = q0 / 64 + 1;
    bf16_t* Pw = Pls + wave * 16 * P_LD;

    for (int t = 0; t < ntiles; ++t) {
        const int k0 = t * 64;
        __syncthreads(); // previous iteration's LDS reads done before restage

        // Stage K tile [64][128] -> Ks (row-major, stride KS_LD)
        for (int i = tid; i < 1024; i += 256) {
            int r = i >> 4, c = (i & 15) * 8;
            *(bf16x8*)&Ks[r * KS_LD + c] =
                *(const bf16x8*)&Kg[(size_t)(base + k0 + r) * D_OUT + hd0 + c];
        }
        // Stage V tile transposed -> Vt[d][key] (stride VT_LD).
        // i = key | (dgroup<<6): lanes take consecutive keys -> LDS writes
        // are consecutive elements (conflict-free).
        for (int i = tid; i < 1024; i += 256) {
            int r = i & 63, c = (i >> 6) * 8;
            bf16x8 v = *(const bf16x8*)&Vg[(size_t)(base + k0 + r) * D_OUT + hd0 + c];
#pragma unroll
            for (int j = 0; j < 8; ++j)
                Vt[(c + j) * VT_LD + r] = v[j];
        }
        __syncthreads();

        // S = Q . K^T  (16 q-rows x 64 keys per wave)
        f32x4 s[4];
#pragma unroll
        for (int nb = 0; nb < 4; ++nb) s[nb] = (f32x4){0.f, 0.f, 0.f, 0.f};
#pragma unroll
        for (int kb = 0; kb < 4; ++kb) {
#pragma unroll
            for (int nb = 0; nb < 4; ++nb) {
                bf16x8 bfrag = *(const bf16x8*)&Ks[(nb * 16 + l16) * KS_LD + kb * 32 + quad * 8];
                s[nb] = __builtin_amdgcn_mfma_f32_16x16x32_bf16(qfrag[kb], bfrag, s[nb], 0, 0, 0);
            }
        }

        // scale + causal mask (key <= qrow allowed)
        const int qrow = q0 + wave * 16 + quad * 4; // + reg
#pragma unroll
        for (int nb = 0; nb < 4; ++nb) {
            int key = k0 + nb * 16 + l16;
#pragma unroll
            for (int r = 0; r < 4; ++r) {
                float v = s[nb][r] * scale;
                s[nb][r] = (key <= qrow + r) ? v : -INFINITY;
            }
        }

        // row max over 64 keys: per-lane over nb, then across 16 lanes
        float rmax[4];
#pragma unroll
        for (int r = 0; r < 4; ++r)
            rmax[r] = fmaxf(fmaxf(s[0][r], s[1][r]), fmaxf(s[2][r], s[3][r]));
#pragma unroll
        for (int msk = 1; msk < 16; msk <<= 1)
#pragma unroll
            for (int r = 0; r < 4; ++r)
                rmax[r] = fmaxf(rmax[r], __shfl_xor(rmax[r], msk, 64));

        float alpha[4], mnew[4];
#pragma unroll
        for (int r = 0; r < 4; ++r) {
            mnew[r] = fmaxf(m_i[r], rmax[r]);
            alpha[r] = __expf(m_i[r] - mnew[r]); // exp(-inf)=0 first tile
            m_i[r] = mnew[r];
        }

        // P = exp(S - m), row sums
        float rs[4] = {0.f, 0.f, 0.f, 0.f};
#pragma unroll
        for (int nb = 0; nb < 4; ++nb)
#pragma unroll
            for (int r = 0; r < 4; ++r) {
                float p = __expf(s[nb][r] - mnew[r]);
                s[nb][r] = p;
                rs[r] += p;
            }
#pragma unroll
        for (int msk = 1; msk < 16; msk <<= 1)
#pragma unroll
            for (int r = 0; r < 4; ++r)
                rs[r] += __shfl_xor(rs[r], msk, 64);
#pragma unroll
        for (int r = 0; r < 4; ++r)
            l_i[r] = l_i[r] * alpha[r] + rs[r];

        // rescale O
#pragma unroll
        for (int ob = 0; ob < 8; ++ob)
#pragma unroll
            for (int r = 0; r < 4; ++r)
                o[ob][r] *= alpha[r];

        // P (C-layout) -> wave-private LDS -> A-layout fragments
#pragma unroll
        for (int nb = 0; nb < 4; ++nb)
#pragma unroll
            for (int r = 0; r < 4; ++r)
                Pw[(quad * 4 + r) * P_LD + nb * 16 + l16] = (bf16_t)s[nb][r];
        __builtin_amdgcn_s_waitcnt(0xc07f); // lgkmcnt(0), wave-private region
        bf16x8 pa0 = *(const bf16x8*)&Pw[l16 * P_LD + 0 + quad * 8];
        bf16x8 pa1 = *(const bf16x8*)&Pw[l16 * P_LD + 32 + quad * 8];

        // O += P . V  (V^T staged: B[k][n] = Vt[ob*16+n][k])
#pragma unroll
        for (int ob = 0; ob < 8; ++ob) {
            bf16x8 b0 = *(const bf16x8*)&Vt[(ob * 16 + l16) * VT_LD + 0 + quad * 8];
            o[ob] = __builtin_amdgcn_mfma_f32_16x16x32_bf16(pa0, b0, o[ob], 0, 0, 0);
            bf16x8 b1 = *(const bf16x8*)&Vt[(ob * 16 + l16) * VT_LD + 32 + quad * 8];
            o[ob] = __builtin_amdgcn_mfma_f32_16x16x32_bf16(pa1, b1, o[ob], 0, 0, 0);
        }
    }

    // epilogue: O /= l, write over query in place
#pragma unroll
    for (int ob = 0; ob < 8; ++ob) {
#pragma unroll
        for (int r = 0; r < 4; ++r) {
            int row = q0 + wave * 16 + quad * 4 + r;
            int col = hd0 + ob * 16 + l16;
            Qg[(size_t)(base + row) * D_OUT + col] = (bf16_t)(o[ob][r] / l_i[r]);
        }
    }
}

extern "C" void kernel_launch(void* const* d_in, const int* in_sizes, int n_in,
                              void* d_out, int out_size, void* d_ws, size_t ws_size,
                              hipStream_t stream)
{
    const float* x    = (const float*)d_in[0];
    const float* w_kv = (const float*)d_in[1];
    const float* b_kv = (const float*)d_in[2];
    const float* w_ku = (const float*)d_in[3];
    const float* b_ku = (const float*)d_in[4];
    const float* w_kr = (const float*)d_in[5];
    const float* b_kr = (const float*)d_in[6];
    const float* w_vu = (const float*)d_in[7];
    const float* b_vu = (const float*)d_in[8];
    const float* w_q  = (const float*)d_in[9];
    const float* b_q  = (const float*)d_in[10];
    const float* w_qu = (const float*)d_in[11];
    const float* b_qu = (const float*)d_in[12];
    const float* w_qr = (const float*)d_in[13];
    const float* b_qr = (const float*)d_in[14];
    const float* w_o  = (const float*)d_in[15];
    const float* b_o  = (const float*)d_in[16];
    float* out = (float*)d_out;

    // d_ws carve-up (bf16): 40 MiB. key lives in d_out scratch (32 MiB f32
    // out buffer holds the 16 MiB bf16 key tile; final GEMM overwrites it).
    bf16* ws    = (bf16*)d_ws;
    bf16* ckv   = ws;                      // [4096, 512]
    bf16* qlat  = ckv   + NTOK * DL;       // [4096, 512]
    bf16* query = qlat  + NTOK * DL;       // [4096, 2048] -> attn out in place
    bf16* value = query + NTOK * D_OUT;    // [4096, 2048]
    bf16* key   = (bf16*)d_out;            // [4096, 2048] scratch

    dim3 blk(16, 16);
    auto grid = [](int M, int N) { return dim3(N / 64, M / 64); };

    gemm_bias_kernel<float, bf16><<<grid(NTOK, DL), blk, 0, stream>>>(
        x, D_IN, w_kv, DL, b_kv, ckv, DL, 0, NTOK, DL, D_IN);
    gemm_bias_kernel<float, bf16><<<grid(NTOK, DL), blk, 0, stream>>>(
        x, D_IN, w_q, DL, b_q, qlat, DL, 0, NTOK, DL, D_IN);
    gemm_bias_kernel<bf16, bf16><<<grid(NTOK, D_OUT / 2), blk, 0, stream>>>(
        ckv, DL, w_ku, D_OUT / 2, b_ku, key, D_OUT, 0, NTOK, D_OUT / 2, DL);
    gemm_bias_kernel<float, bf16><<<grid(NTOK, D_OUT / 2), blk, 0, stream>>>(
        x, D_IN, w_kr, D_OUT / 2, b_kr, key, D_OUT, D_OUT / 2, NTOK, D_OUT / 2, D_IN);
    gemm_bias_kernel<bf16, bf16><<<grid(NTOK, D_OUT / 2), blk, 0, stream>>>(
        qlat, DL, w_qu, D_OUT / 2, b_qu, query, D_OUT, 0, NTOK, D_OUT / 2, DL);
    gemm_bias_kernel<bf16, bf16><<<grid(NTOK, D_OUT / 2), blk, 0, stream>>>(
        qlat, DL, w_qr, D_OUT / 2, b_qr, query, D_OUT, D_OUT / 2, NTOK, D_OUT / 2, DL);
    gemm_bias_kernel<bf16, bf16><<<grid(NTOK, D_OUT), blk, 0, stream>>>(
        ckv, DL, w_vu, D_OUT, b_vu, value, D_OUT, 0, NTOK, D_OUT, DL);

    attn_mfma_kernel<<<dim3(SEQ / 64, NUM_HEAD, BATCH), 256, 0, stream>>>(
        (bf16_t*)query, (const bf16_t*)key, (const bf16_t*)value);

    gemm_bias_kernel<bf16, float><<<grid(NTOK, D_OUT), blk, 0, stream>>>(
        query, D_OUT, w_o, D_OUT, b_o, out, D_OUT, 0, NTOK, D_OUT, D_OUT);
}

// Round 5
// 672.218 us; speedup vs baseline: 10.4724x; 3.2327x over previous
//
#include <hip/hip_runtime.h>
#include <hip/hip_bf16.h>

typedef __hip_bfloat16 bf16;
typedef __bf16 bf16_t;
typedef __bf16 bf16x8 __attribute__((ext_vector_type(8)));
typedef float f32x4 __attribute__((ext_vector_type(4)));

#define D_IN 2048
#define D_OUT 2048
#define DL 512
#define NUM_HEAD 16
#define SEQ 2048
#define HEAD_DIM 128
#define BATCH 2
#define NTOK (BATCH * SEQ) // 4096

__device__ __forceinline__ void stf(float* p, float v) { *p = v; }
__device__ __forceinline__ void stf(bf16_t* p, float v) { *p = (bf16_t)v; }

__device__ __forceinline__ void async_cp16(const bf16_t* g, bf16_t* l) {
    __builtin_amdgcn_global_load_lds(
        (const __attribute__((address_space(1))) void*)g,
        (__attribute__((address_space(3))) void*)l, 16, 0, 0);
}

// ---------------------------------------------------------------------------
// f32 -> bf16 elementwise convert (x pre-pass). n multiple of 1024.
// ---------------------------------------------------------------------------
__global__ __launch_bounds__(256) void cvt_kernel(
    const float* __restrict__ src, bf16_t* __restrict__ dst)
{
    int i = (blockIdx.x * 256 + threadIdx.x) * 4;
    float4 v = *(const float4*)&src[i];
    bf16_t o[4] = {(bf16_t)v.x, (bf16_t)v.y, (bf16_t)v.z, (bf16_t)v.w};
    *(ulong1*)&dst[i] = *(ulong1*)o;
}

// ---------------------------------------------------------------------------
// Weight transpose + convert: Wt[n][k] = (bf16)W[k][n]. 32x32 LDS tiles.
// block (32,8), grid (N/32, K/32).
// ---------------------------------------------------------------------------
__global__ __launch_bounds__(256) void transpose_cvt_kernel(
    const float* __restrict__ W, bf16_t* __restrict__ Wt, int K, int N)
{
    __shared__ float t[32][33];
    const int n0 = blockIdx.x * 32, k0 = blockIdx.y * 32;
    const int c = threadIdx.x, r0 = threadIdx.y;
#pragma unroll
    for (int rr = 0; rr < 32; rr += 8)
        t[r0 + rr][c] = W[(size_t)(k0 + r0 + rr) * N + n0 + c];
    __syncthreads();
#pragma unroll
    for (int rr = 0; rr < 32; rr += 8)
        Wt[(size_t)(n0 + r0 + rr) * K + k0 + c] = (bf16_t)t[c][r0 + rr];
}

// ---------------------------------------------------------------------------
// MFMA GEMM: C[m, col0+n] = A[m,:K] @ Wt[n,:K]^T + bias[n]
// A: [M,K] bf16 row-major; Wt: [N,K] bf16 row-major (pre-transposed weights).
// Block 256 = 4 waves (2x2), tile 128x128, BK=32, global_load_lds width=16.
// Per K-tile per wave: 4+4 ds_read_b128 frags + 16 mfma_f32_16x16x32_bf16.
// grid (N/128, M/128).
// ---------------------------------------------------------------------------
template <typename TC>
__global__ __launch_bounds__(256) void gemm_mfma_kernel(
    const bf16_t* __restrict__ A, int lda,
    const bf16_t* __restrict__ Wt, int ldwt,
    const float* __restrict__ bias,
    TC* __restrict__ C, int ldc, int col0, int K)
{
    __shared__ __align__(16) bf16_t As[128 * 32]; // 8 KiB
    __shared__ __align__(16) bf16_t Bs[128 * 32]; // 8 KiB

    const int tid  = threadIdx.x;
    const int wave = tid >> 6, lane = tid & 63;
    const int quad = lane >> 4, l16 = lane & 15;
    const int wm = wave & 1, wn = wave >> 1;
    const int m0 = blockIdx.y * 128;
    const int n0 = blockIdx.x * 128;

    // staging: thread tid covers 16B chunk at LDS elem offset tid*8 (rows
    // 0..63) and 2048 + tid*8 (rows 64..127) — linear in lane order, exactly
    // the wave-uniform-base + lane*16B layout global_load_lds scatters to.
    const int r0 = tid >> 2, c0 = (tid & 3) * 8;
    const bf16_t* Ap0 = A  + (size_t)(m0 + r0)      * lda  + c0;
    const bf16_t* Ap1 = A  + (size_t)(m0 + r0 + 64) * lda  + c0;
    const bf16_t* Bp0 = Wt + (size_t)(n0 + r0)      * ldwt + c0;
    const bf16_t* Bp1 = Wt + (size_t)(n0 + r0 + 64) * ldwt + c0;

    f32x4 acc[4][4];
#pragma unroll
    for (int i = 0; i < 4; ++i)
#pragma unroll
        for (int j = 0; j < 4; ++j) acc[i][j] = (f32x4){0.f, 0.f, 0.f, 0.f};

    for (int k0 = 0; k0 < K; k0 += 32) {
        __syncthreads(); // prior tile's frag reads complete before restage
        async_cp16(Ap0 + k0, As + tid * 8);
        async_cp16(Ap1 + k0, As + 2048 + tid * 8);
        async_cp16(Bp0 + k0, Bs + tid * 8);
        async_cp16(Bp1 + k0, Bs + 2048 + tid * 8);
        __syncthreads(); // drains vmcnt -> staging visible

        bf16x8 af[4], bfr[4];
#pragma unroll
        for (int t = 0; t < 4; ++t) {
            af[t]  = *(const bf16x8*)&As[(wm * 64 + t * 16 + l16) * 32 + quad * 8];
            bfr[t] = *(const bf16x8*)&Bs[(wn * 64 + t * 16 + l16) * 32 + quad * 8];
        }
#pragma unroll
        for (int mt = 0; mt < 4; ++mt)
#pragma unroll
            for (int nt = 0; nt < 4; ++nt)
                acc[mt][nt] = __builtin_amdgcn_mfma_f32_16x16x32_bf16(
                    af[mt], bfr[nt], acc[mt][nt], 0, 0, 0);
    }

    // epilogue: C/D layout col = l16, row = quad*4 + r
    const int mrow = m0 + wm * 64 + quad * 4;
#pragma unroll
    for (int mt = 0; mt < 4; ++mt)
#pragma unroll
        for (int nt = 0; nt < 4; ++nt) {
            int col = n0 + wn * 64 + nt * 16 + l16;
            float bv = bias[col];
#pragma unroll
            for (int r = 0; r < 4; ++r)
                stf(&C[(size_t)(mrow + mt * 16 + r) * ldc + col0 + col],
                    acc[mt][nt][r] + bv);
        }
}

// ---------------------------------------------------------------------------
// MFMA flash attention (unchanged from R4). Block = 4 waves; Q-tile 64,
// K-tile 64; output written in place over query.
// ---------------------------------------------------------------------------
#define KS_LD 136
#define VT_LD 72
#define P_LD  72

__global__ __launch_bounds__(256) void attn_mfma_kernel(
    bf16_t* __restrict__ Qg, const bf16_t* __restrict__ Kg,
    const bf16_t* __restrict__ Vg)
{
    __shared__ __align__(16) bf16_t Ks[64 * KS_LD];
    __shared__ __align__(16) bf16_t Vt[128 * VT_LD];
    __shared__ __align__(16) bf16_t Pls[4 * 16 * P_LD];

    const int tid  = threadIdx.x;
    const int wave = tid >> 6;
    const int lane = tid & 63;
    const int quad = lane >> 4;
    const int l16  = lane & 15;

    const int q0   = blockIdx.x * 64;
    const int h    = blockIdx.y;
    const int b    = blockIdx.z;
    const int base = b * SEQ;
    const int hd0  = h * HEAD_DIM;

    const float scale = 0.08838834764831845f;

    bf16x8 qfrag[4];
    {
        const bf16_t* qrow = Qg + (size_t)(base + q0 + wave * 16 + l16) * D_OUT + hd0;
#pragma unroll
        for (int kb = 0; kb < 4; ++kb)
            qfrag[kb] = *(const bf16x8*)(qrow + kb * 32 + quad * 8);
    }

    f32x4 o[8];
#pragma unroll
    for (int ob = 0; ob < 8; ++ob) o[ob] = (f32x4){0.f, 0.f, 0.f, 0.f};
    float m_i[4] = {-INFINITY, -INFINITY, -INFINITY, -INFINITY};
    float l_i[4] = {0.f, 0.f, 0.f, 0.f};

    const int ntiles = q0 / 64 + 1;
    bf16_t* Pw = Pls + wave * 16 * P_LD;

    for (int t = 0; t < ntiles; ++t) {
        const int k0 = t * 64;
        __syncthreads();

        for (int i = tid; i < 1024; i += 256) {
            int r = i >> 4, c = (i & 15) * 8;
            *(bf16x8*)&Ks[r * KS_LD + c] =
                *(const bf16x8*)&Kg[(size_t)(base + k0 + r) * D_OUT + hd0 + c];
        }
        for (int i = tid; i < 1024; i += 256) {
            int r = i & 63, c = (i >> 6) * 8;
            bf16x8 v = *(const bf16x8*)&Vg[(size_t)(base + k0 + r) * D_OUT + hd0 + c];
#pragma unroll
            for (int j = 0; j < 8; ++j)
                Vt[(c + j) * VT_LD + r] = v[j];
        }
        __syncthreads();

        f32x4 s[4];
#pragma unroll
        for (int nb = 0; nb < 4; ++nb) s[nb] = (f32x4){0.f, 0.f, 0.f, 0.f};
#pragma unroll
        for (int kb = 0; kb < 4; ++kb) {
#pragma unroll
            for (int nb = 0; nb < 4; ++nb) {
                bf16x8 bfrag = *(const bf16x8*)&Ks[(nb * 16 + l16) * KS_LD + kb * 32 + quad * 8];
                s[nb] = __builtin_amdgcn_mfma_f32_16x16x32_bf16(qfrag[kb], bfrag, s[nb], 0, 0, 0);
            }
        }

        const int qrow = q0 + wave * 16 + quad * 4;
#pragma unroll
        for (int nb = 0; nb < 4; ++nb) {
            int key = k0 + nb * 16 + l16;
#pragma unroll
            for (int r = 0; r < 4; ++r) {
                float v = s[nb][r] * scale;
                s[nb][r] = (key <= qrow + r) ? v : -INFINITY;
            }
        }

        float rmax[4];
#pragma unroll
        for (int r = 0; r < 4; ++r)
            rmax[r] = fmaxf(fmaxf(s[0][r], s[1][r]), fmaxf(s[2][r], s[3][r]));
#pragma unroll
        for (int msk = 1; msk < 16; msk <<= 1)
#pragma unroll
            for (int r = 0; r < 4; ++r)
                rmax[r] = fmaxf(rmax[r], __shfl_xor(rmax[r], msk, 64));

        float alpha[4], mnew[4];
#pragma unroll
        for (int r = 0; r < 4; ++r) {
            mnew[r] = fmaxf(m_i[r], rmax[r]);
            alpha[r] = __expf(m_i[r] - mnew[r]);
            m_i[r] = mnew[r];
        }

        float rs[4] = {0.f, 0.f, 0.f, 0.f};
#pragma unroll
        for (int nb = 0; nb < 4; ++nb)
#pragma unroll
            for (int r = 0; r < 4; ++r) {
                float p = __expf(s[nb][r] - mnew[r]);
                s[nb][r] = p;
                rs[r] += p;
            }
#pragma unroll
        for (int msk = 1; msk < 16; msk <<= 1)
#pragma unroll
            for (int r = 0; r < 4; ++r)
                rs[r] += __shfl_xor(rs[r], msk, 64);
#pragma unroll
        for (int r = 0; r < 4; ++r)
            l_i[r] = l_i[r] * alpha[r] + rs[r];

#pragma unroll
        for (int ob = 0; ob < 8; ++ob)
#pragma unroll
            for (int r = 0; r < 4; ++r)
                o[ob][r] *= alpha[r];

#pragma unroll
        for (int nb = 0; nb < 4; ++nb)
#pragma unroll
            for (int r = 0; r < 4; ++r)
                Pw[(quad * 4 + r) * P_LD + nb * 16 + l16] = (bf16_t)s[nb][r];
        __builtin_amdgcn_s_waitcnt(0xc07f);
        bf16x8 pa0 = *(const bf16x8*)&Pw[l16 * P_LD + 0 + quad * 8];
        bf16x8 pa1 = *(const bf16x8*)&Pw[l16 * P_LD + 32 + quad * 8];

#pragma unroll
        for (int ob = 0; ob < 8; ++ob) {
            bf16x8 b0 = *(const bf16x8*)&Vt[(ob * 16 + l16) * VT_LD + 0 + quad * 8];
            o[ob] = __builtin_amdgcn_mfma_f32_16x16x32_bf16(pa0, b0, o[ob], 0, 0, 0);
            bf16x8 b1 = *(const bf16x8*)&Vt[(ob * 16 + l16) * VT_LD + 32 + quad * 8];
            o[ob] = __builtin_amdgcn_mfma_f32_16x16x32_bf16(pa1, b1, o[ob], 0, 0, 0);
        }
    }

#pragma unroll
    for (int ob = 0; ob < 8; ++ob) {
#pragma unroll
        for (int r = 0; r < 4; ++r) {
            int row = q0 + wave * 16 + quad * 4 + r;
            int col = hd0 + ob * 16 + l16;
            Qg[(size_t)(base + row) * D_OUT + col] = (bf16_t)(o[ob][r] / l_i[r]);
        }
    }
}

extern "C" void kernel_launch(void* const* d_in, const int* in_sizes, int n_in,
                              void* d_out, int out_size, void* d_ws, size_t ws_size,
                              hipStream_t stream)
{
    const float* x    = (const float*)d_in[0];
    const float* w_kv = (const float*)d_in[1];
    const float* b_kv = (const float*)d_in[2];
    const float* w_ku = (const float*)d_in[3];
    const float* b_ku = (const float*)d_in[4];
    const float* w_kr = (const float*)d_in[5];
    const float* b_kr = (const float*)d_in[6];
    const float* w_vu = (const float*)d_in[7];
    const float* b_vu = (const float*)d_in[8];
    const float* w_q  = (const float*)d_in[9];
    const float* b_q  = (const float*)d_in[10];
    const float* w_qu = (const float*)d_in[11];
    const float* b_qu = (const float*)d_in[12];
    const float* w_qr = (const float*)d_in[13];
    const float* b_qr = (const float*)d_in[14];
    const float* w_o  = (const float*)d_in[15];
    const float* b_o  = (const float*)d_in[16];
    float* out = (float*)d_out;

    // ws carve-up (bf16), total 61 MiB:
    //   ckv 4 + qlat 4 + query 16 + value 16 + Wt's 21.
    // d_out (32 MiB f32) doubles as scratch: key bf16 [0,16MiB),
    // xb bf16 [16,32MiB) — both dead before the final GEMM overwrites d_out.
    bf16_t* ws    = (bf16_t*)d_ws;
    bf16_t* ckv   = ws;                     // [4096, 512]
    bf16_t* qlat  = ckv   + NTOK * DL;      // [4096, 512]
    bf16_t* query = qlat  + NTOK * DL;      // [4096, 2048] -> attn out in place
    bf16_t* value = query + NTOK * D_OUT;   // [4096, 2048]
    bf16_t* wt_kv = value + NTOK * D_OUT;   // [512, 2048]
    bf16_t* wt_ku = wt_kv + 512 * 2048;     // [1024, 512]
    bf16_t* wt_kr = wt_ku + 1024 * 512;     // [1024, 2048]
    bf16_t* wt_vu = wt_kr + 1024 * 2048;    // [2048, 512]
    bf16_t* wt_q  = wt_vu + 2048 * 512;     // [512, 2048]
    bf16_t* wt_qu = wt_q  + 512 * 2048;     // [1024, 512]
    bf16_t* wt_qr = wt_qu + 1024 * 512;     // [1024, 512]
    bf16_t* wt_o  = wt_qr + 1024 * 512;     // [2048, 2048]
    bf16_t* key   = (bf16_t*)d_out;         // [4096, 2048]
    bf16_t* xb    = key + NTOK * D_OUT;     // [4096, 2048]

    // 1. convert x -> bf16
    cvt_kernel<<<NTOK * D_IN / 1024, 256, 0, stream>>>(x, xb);

    // 2. transpose+convert all weights: Wt[n][k] = W[k][n]
    dim3 tb(32, 8);
    transpose_cvt_kernel<<<dim3(512 / 32, 2048 / 32), tb, 0, stream>>>(w_kv, wt_kv, 2048, 512);
    transpose_cvt_kernel<<<dim3(1024 / 32, 512 / 32), tb, 0, stream>>>(w_ku, wt_ku, 512, 1024);
    transpose_cvt_kernel<<<dim3(1024 / 32, 2048 / 32), tb, 0, stream>>>(w_kr, wt_kr, 2048, 1024);
    transpose_cvt_kernel<<<dim3(2048 / 32, 512 / 32), tb, 0, stream>>>(w_vu, wt_vu, 512, 2048);
    transpose_cvt_kernel<<<dim3(512 / 32, 2048 / 32), tb, 0, stream>>>(w_q, wt_q, 2048, 512);
    transpose_cvt_kernel<<<dim3(1024 / 32, 512 / 32), tb, 0, stream>>>(w_qu, wt_qu, 512, 1024);
    transpose_cvt_kernel<<<dim3(1024 / 32, 512 / 32), tb, 0, stream>>>(w_qr, wt_qr, 512, 1024);
    transpose_cvt_kernel<<<dim3(2048 / 32, 2048 / 32), tb, 0, stream>>>(w_o, wt_o, 2048, 2048);

    // 3. projection GEMMs (all A-operands bf16, weights pre-transposed)
    auto grid = [](int N) { return dim3(N / 128, NTOK / 128); };
    gemm_mfma_kernel<bf16_t><<<grid(DL), 256, 0, stream>>>(
        xb, D_IN, wt_kv, D_IN, b_kv, ckv, DL, 0, D_IN);
    gemm_mfma_kernel<bf16_t><<<grid(DL), 256, 0, stream>>>(
        xb, D_IN, wt_q, D_IN, b_q, qlat, DL, 0, D_IN);
    gemm_mfma_kernel<bf16_t><<<grid(1024), 256, 0, stream>>>(
        ckv, DL, wt_ku, DL, b_ku, key, D_OUT, 0, DL);
    gemm_mfma_kernel<bf16_t><<<grid(1024), 256, 0, stream>>>(
        xb, D_IN, wt_kr, D_IN, b_kr, key, D_OUT, 1024, D_IN);
    gemm_mfma_kernel<bf16_t><<<grid(1024), 256, 0, stream>>>(
        qlat, DL, wt_qu, DL, b_qu, query, D_OUT, 0, DL);
    gemm_mfma_kernel<bf16_t><<<grid(1024), 256, 0, stream>>>(
        qlat, DL, wt_qr, DL, b_qr, query, D_OUT, 1024, DL);
    gemm_mfma_kernel<bf16_t><<<grid(D_OUT), 256, 0, stream>>>(
        ckv, DL, wt_vu, DL, b_vu, value, D_OUT, 0, DL);

    // 4. flash attention (in place over query)
    attn_mfma_kernel<<<dim3(SEQ / 64, NUM_HEAD, BATCH), 256, 0, stream>>>(
        query, key, value);

    // 5. out = attno @ w_o + b_o (f32 output)
    gemm_mfma_kernel<float><<<grid(D_OUT), 256, 0, stream>>>(
        query, D_OUT, wt_o, D_OUT, b_o, out, D_OUT, 0, D_OUT);
}

// Round 6
// 465.927 us; speedup vs baseline: 15.1091x; 1.4428x over previous
//
#include <hip/hip_runtime.h>
#include <hip/hip_bf16.h>

typedef __hip_bfloat16 bf16;
typedef __bf16 bf16_t;
typedef __bf16 bf16x8 __attribute__((ext_vector_type(8)));
typedef float f32x4 __attribute__((ext_vector_type(4)));

#define D_IN 2048
#define D_OUT 2048
#define DL 512
#define NUM_HEAD 16
#define SEQ 2048
#define HEAD_DIM 128
#define BATCH 2
#define NTOK (BATCH * SEQ) // 4096

__device__ __forceinline__ void stf(float* p, float v) { *p = v; }
__device__ __forceinline__ void stf(bf16_t* p, float v) { *p = (bf16_t)v; }

__device__ __forceinline__ void async_cp16(const bf16_t* g, bf16_t* l) {
    __builtin_amdgcn_global_load_lds(
        (const __attribute__((address_space(1))) void*)g,
        (__attribute__((address_space(3))) void*)l, 16, 0, 0);
}

// ---------------------------------------------------------------------------
// Fused prep kernel: blocks [0, CVTB) convert x f32->bf16; blocks
// [CVTB, CVTB+TRB) do weight transpose+convert tiles; last block concats
// b_kv|b_q into bkvq. One launch replaces 10.
// ---------------------------------------------------------------------------
#define CVTB 8192          // 4096*2048 / 1024
#define NTOPS 8

struct TOp { const float* W; bf16_t* Wt; int K, N, nx, nblk; };
struct TOps { TOp op[NTOPS]; };

__global__ __launch_bounds__(256) void prep_kernel(
    const float* __restrict__ x, bf16_t* __restrict__ xb,
    TOps ops,
    const float* __restrict__ b_kv, const float* __restrict__ b_q,
    float* __restrict__ bkvq, int trb)
{
    const int tid = threadIdx.x;
    int blk = blockIdx.x;

    if (blk < CVTB) {
        int i = (blk * 256 + tid) * 4;
        float4 v = *(const float4*)&x[i];
        bf16_t o[4] = {(bf16_t)v.x, (bf16_t)v.y, (bf16_t)v.z, (bf16_t)v.w};
        *(ulong1*)&xb[i] = *(ulong1*)o;
        return;
    }
    blk -= CVTB;
    if (blk < trb) {
        int op = 0;
        while (blk >= ops.op[op].nblk) { blk -= ops.op[op].nblk; ++op; }
        const TOp& t = ops.op[op];
        const int n0 = (blk % t.nx) * 32, k0 = (blk / t.nx) * 32;
        __shared__ float tl[32][33];
        const int c = tid & 31, r0 = tid >> 5;
#pragma unroll
        for (int rr = 0; rr < 32; rr += 8)
            tl[r0 + rr][c] = t.W[(size_t)(k0 + r0 + rr) * t.N + n0 + c];
        __syncthreads();
#pragma unroll
        for (int rr = 0; rr < 32; rr += 8)
            t.Wt[(size_t)(n0 + r0 + rr) * t.K + k0 + c] = (bf16_t)tl[c][r0 + rr];
        return;
    }
    // bias concat: bkvq = b_kv ++ b_q (1024 floats)
#pragma unroll
    for (int j = 0; j < 4; ++j) {
        int i = tid + j * 256;
        bkvq[i] = (i < DL) ? b_kv[i] : b_q[i - DL];
    }
}

// ---------------------------------------------------------------------------
// Multi-op MFMA GEMM: flattened 1-D grid over a descriptor list.
// Per op: C[m, col0+n] = A[m,:K] @ Wt[n,:K]^T + bias[n], M = 4096 always,
// Wt row stride = K. Block 256 = 4 waves (2x2), tile 128x128, BK=32,
// global_load_lds width=16, 16x mfma_f32_16x16x32_bf16 per K-step per wave.
// ---------------------------------------------------------------------------
struct GOp { const bf16_t* A; const bf16_t* Wt; const float* bias;
             void* C; int lda, K, col0, ldc, nx, nblk; };
template <int N> struct GOps { GOp op[N]; };

template <typename TC, int NOPS>
__global__ __launch_bounds__(256) void gemm_multi_kernel(GOps<NOPS> ops)
{
    __shared__ __align__(16) bf16_t As[128 * 32];
    __shared__ __align__(16) bf16_t Bs[128 * 32];

    int blk = blockIdx.x;
    int opi = 0;
    while (blk >= ops.op[opi].nblk) { blk -= ops.op[opi].nblk; ++opi; }
    const GOp& g = ops.op[opi];

    const int tid  = threadIdx.x;
    const int wave = tid >> 6, lane = tid & 63;
    const int quad = lane >> 4, l16 = lane & 15;
    const int wm = wave & 1, wn = wave >> 1;
    const int m0 = (blk / g.nx) * 128;
    const int n0 = (blk % g.nx) * 128;

    const int r0 = tid >> 2, c0 = (tid & 3) * 8;
    const bf16_t* Ap0 = g.A  + (size_t)(m0 + r0)      * g.lda + c0;
    const bf16_t* Ap1 = g.A  + (size_t)(m0 + r0 + 64) * g.lda + c0;
    const bf16_t* Bp0 = g.Wt + (size_t)(n0 + r0)      * g.K   + c0;
    const bf16_t* Bp1 = g.Wt + (size_t)(n0 + r0 + 64) * g.K   + c0;

    f32x4 acc[4][4];
#pragma unroll
    for (int i = 0; i < 4; ++i)
#pragma unroll
        for (int j = 0; j < 4; ++j) acc[i][j] = (f32x4){0.f, 0.f, 0.f, 0.f};

    for (int k0 = 0; k0 < g.K; k0 += 32) {
        __syncthreads();
        async_cp16(Ap0 + k0, As + tid * 8);
        async_cp16(Ap1 + k0, As + 2048 + tid * 8);
        async_cp16(Bp0 + k0, Bs + tid * 8);
        async_cp16(Bp1 + k0, Bs + 2048 + tid * 8);
        __syncthreads();

        bf16x8 af[4], bfr[4];
#pragma unroll
        for (int t = 0; t < 4; ++t) {
            af[t]  = *(const bf16x8*)&As[(wm * 64 + t * 16 + l16) * 32 + quad * 8];
            bfr[t] = *(const bf16x8*)&Bs[(wn * 64 + t * 16 + l16) * 32 + quad * 8];
        }
#pragma unroll
        for (int mt = 0; mt < 4; ++mt)
#pragma unroll
            for (int nt = 0; nt < 4; ++nt)
                acc[mt][nt] = __builtin_amdgcn_mfma_f32_16x16x32_bf16(
                    af[mt], bfr[nt], acc[mt][nt], 0, 0, 0);
    }

    TC* C = (TC*)g.C;
    const int mrow = m0 + wm * 64 + quad * 4;
#pragma unroll
    for (int mt = 0; mt < 4; ++mt)
#pragma unroll
        for (int nt = 0; nt < 4; ++nt) {
            int col = n0 + wn * 64 + nt * 16 + l16;
            float bv = g.bias[col];
#pragma unroll
            for (int r = 0; r < 4; ++r)
                stf(&C[(size_t)(mrow + mt * 16 + r) * g.ldc + g.col0 + col],
                    acc[mt][nt][r] + bv);
        }
}

// ---------------------------------------------------------------------------
// MFMA flash attention with causal load balancing: block p handles q-tiles
// p and 31-p sequentially -> uniform 33 k-tile iterations per block; grid
// (16, 16, 2) = 512 blocks = exactly 2 resident blocks/CU, no tail.
// Per-tile flow unchanged from R4/R5 (verified). Output in place over query.
// ---------------------------------------------------------------------------
#define KS_LD 136
#define VT_LD 72
#define P_LD  72
#define NQT   (SEQ / 64) // 32

__global__ __launch_bounds__(256) void attn_mfma_kernel(
    bf16_t* __restrict__ Qg, const bf16_t* __restrict__ Kg,
    const bf16_t* __restrict__ Vg)
{
    __shared__ __align__(16) bf16_t Ks[64 * KS_LD];
    __shared__ __align__(16) bf16_t Vt[128 * VT_LD];
    __shared__ __align__(16) bf16_t Pls[4 * 16 * P_LD];

    const int tid  = threadIdx.x;
    const int wave = tid >> 6;
    const int lane = tid & 63;
    const int quad = lane >> 4;
    const int l16  = lane & 15;

    const int h    = blockIdx.y;
    const int b    = blockIdx.z;
    const int base = b * SEQ;
    const int hd0  = h * HEAD_DIM;

    const float scale = 0.08838834764831845f;
    bf16_t* Pw = Pls + wave * 16 * P_LD;

    for (int phase = 0; phase < 2; ++phase) {
        const int qt = phase == 0 ? blockIdx.x : (NQT - 1 - blockIdx.x);
        const int q0 = qt * 64;
        const int ntiles = qt + 1;

        bf16x8 qfrag[4];
        {
            const bf16_t* qrow = Qg + (size_t)(base + q0 + wave * 16 + l16) * D_OUT + hd0;
#pragma unroll
            for (int kb = 0; kb < 4; ++kb)
                qfrag[kb] = *(const bf16x8*)(qrow + kb * 32 + quad * 8);
        }

        f32x4 o[8];
#pragma unroll
        for (int ob = 0; ob < 8; ++ob) o[ob] = (f32x4){0.f, 0.f, 0.f, 0.f};
        float m_i[4] = {-INFINITY, -INFINITY, -INFINITY, -INFINITY};
        float l_i[4] = {0.f, 0.f, 0.f, 0.f};

        for (int t = 0; t < ntiles; ++t) {
            const int k0 = t * 64;
            __syncthreads(); // prior iteration/phase LDS reads done

            for (int i = tid; i < 1024; i += 256) {
                int r = i >> 4, c = (i & 15) * 8;
                *(bf16x8*)&Ks[r * KS_LD + c] =
                    *(const bf16x8*)&Kg[(size_t)(base + k0 + r) * D_OUT + hd0 + c];
            }
            for (int i = tid; i < 1024; i += 256) {
                int r = i & 63, c = (i >> 6) * 8;
                bf16x8 v = *(const bf16x8*)&Vg[(size_t)(base + k0 + r) * D_OUT + hd0 + c];
#pragma unroll
                for (int j = 0; j < 8; ++j)
                    Vt[(c + j) * VT_LD + r] = v[j];
            }
            __syncthreads();

            f32x4 s[4];
#pragma unroll
            for (int nb = 0; nb < 4; ++nb) s[nb] = (f32x4){0.f, 0.f, 0.f, 0.f};
#pragma unroll
            for (int kb = 0; kb < 4; ++kb) {
#pragma unroll
                for (int nb = 0; nb < 4; ++nb) {
                    bf16x8 bfrag = *(const bf16x8*)&Ks[(nb * 16 + l16) * KS_LD + kb * 32 + quad * 8];
                    s[nb] = __builtin_amdgcn_mfma_f32_16x16x32_bf16(qfrag[kb], bfrag, s[nb], 0, 0, 0);
                }
            }

            const int qrow = q0 + wave * 16 + quad * 4;
#pragma unroll
            for (int nb = 0; nb < 4; ++nb) {
                int key = k0 + nb * 16 + l16;
#pragma unroll
                for (int r = 0; r < 4; ++r) {
                    float v = s[nb][r] * scale;
                    s[nb][r] = (key <= qrow + r) ? v : -INFINITY;
                }
            }

            float rmax[4];
#pragma unroll
            for (int r = 0; r < 4; ++r)
                rmax[r] = fmaxf(fmaxf(s[0][r], s[1][r]), fmaxf(s[2][r], s[3][r]));
#pragma unroll
            for (int msk = 1; msk < 16; msk <<= 1)
#pragma unroll
                for (int r = 0; r < 4; ++r)
                    rmax[r] = fmaxf(rmax[r], __shfl_xor(rmax[r], msk, 64));

            float alpha[4], mnew[4];
#pragma unroll
            for (int r = 0; r < 4; ++r) {
                mnew[r] = fmaxf(m_i[r], rmax[r]);
                alpha[r] = __expf(m_i[r] - mnew[r]);
                m_i[r] = mnew[r];
            }

            float rs[4] = {0.f, 0.f, 0.f, 0.f};
#pragma unroll
            for (int nb = 0; nb < 4; ++nb)
#pragma unroll
                for (int r = 0; r < 4; ++r) {
                    float p = __expf(s[nb][r] - mnew[r]);
                    s[nb][r] = p;
                    rs[r] += p;
                }
#pragma unroll
            for (int msk = 1; msk < 16; msk <<= 1)
#pragma unroll
                for (int r = 0; r < 4; ++r)
                    rs[r] += __shfl_xor(rs[r], msk, 64);
#pragma unroll
            for (int r = 0; r < 4; ++r)
                l_i[r] = l_i[r] * alpha[r] + rs[r];

#pragma unroll
            for (int ob = 0; ob < 8; ++ob)
#pragma unroll
                for (int r = 0; r < 4; ++r)
                    o[ob][r] *= alpha[r];

#pragma unroll
            for (int nb = 0; nb < 4; ++nb)
#pragma unroll
                for (int r = 0; r < 4; ++r)
                    Pw[(quad * 4 + r) * P_LD + nb * 16 + l16] = (bf16_t)s[nb][r];
            __builtin_amdgcn_s_waitcnt(0xc07f); // lgkmcnt(0), wave-private
            bf16x8 pa0 = *(const bf16x8*)&Pw[l16 * P_LD + 0 + quad * 8];
            bf16x8 pa1 = *(const bf16x8*)&Pw[l16 * P_LD + 32 + quad * 8];

#pragma unroll
            for (int ob = 0; ob < 8; ++ob) {
                bf16x8 b0 = *(const bf16x8*)&Vt[(ob * 16 + l16) * VT_LD + 0 + quad * 8];
                o[ob] = __builtin_amdgcn_mfma_f32_16x16x32_bf16(pa0, b0, o[ob], 0, 0, 0);
                bf16x8 b1 = *(const bf16x8*)&Vt[(ob * 16 + l16) * VT_LD + 32 + quad * 8];
                o[ob] = __builtin_amdgcn_mfma_f32_16x16x32_bf16(pa1, b1, o[ob], 0, 0, 0);
            }
        }

#pragma unroll
        for (int ob = 0; ob < 8; ++ob) {
#pragma unroll
            for (int r = 0; r < 4; ++r) {
                int row = q0 + wave * 16 + quad * 4 + r;
                int col = hd0 + ob * 16 + l16;
                Qg[(size_t)(base + row) * D_OUT + col] = (bf16_t)(o[ob][r] / l_i[r]);
            }
        }
    }
}

extern "C" void kernel_launch(void* const* d_in, const int* in_sizes, int n_in,
                              void* d_out, int out_size, void* d_ws, size_t ws_size,
                              hipStream_t stream)
{
    const float* x    = (const float*)d_in[0];
    const float* w_kv = (const float*)d_in[1];
    const float* b_kv = (const float*)d_in[2];
    const float* w_ku = (const float*)d_in[3];
    const float* b_ku = (const float*)d_in[4];
    const float* w_kr = (const float*)d_in[5];
    const float* b_kr = (const float*)d_in[6];
    const float* w_vu = (const float*)d_in[7];
    const float* b_vu = (const float*)d_in[8];
    const float* w_q  = (const float*)d_in[9];
    const float* b_q  = (const float*)d_in[10];
    const float* w_qu = (const float*)d_in[11];
    const float* b_qu = (const float*)d_in[12];
    const float* w_qr = (const float*)d_in[13];
    const float* b_qr = (const float*)d_in[14];
    const float* w_o  = (const float*)d_in[15];
    const float* b_o  = (const float*)d_in[16];
    float* out = (float*)d_out;

    // ws carve-up (bf16): ckvq 8 MiB + query 16 + value 16 + Wt's 21 + bias.
    // d_out (33.5 MiB f32) doubles as scratch: key bf16 [0,16.7M), xb bf16
    // [16.7M, 33.5M) — both dead before the final GEMM overwrites d_out.
    bf16_t* ws    = (bf16_t*)d_ws;
    bf16_t* ckvq  = ws;                     // [4096, 1024]: ckv | qlat
    bf16_t* query = ckvq  + NTOK * 1024;    // [4096, 2048] -> attn out in place
    bf16_t* value = query + NTOK * D_OUT;   // [4096, 2048]
    bf16_t* wt_kv = value + NTOK * D_OUT;   // [512, 2048]
    bf16_t* wt_q  = wt_kv + 512 * 2048;     // [512, 2048] (contig after wt_kv)
    bf16_t* wt_ku = wt_q  + 512 * 2048;     // [1024, 512]
    bf16_t* wt_kr = wt_ku + 1024 * 512;     // [1024, 2048]
    bf16_t* wt_vu = wt_kr + 1024 * 2048;    // [2048, 512]
    bf16_t* wt_qu = wt_vu + 2048 * 512;     // [1024, 512]
    bf16_t* wt_qr = wt_qu + 1024 * 512;     // [1024, 512]
    bf16_t* wt_o  = wt_qr + 1024 * 512;     // [2048, 2048]
    float*  bkvq  = (float*)(wt_o + 2048 * 2048); // [1024]
    bf16_t* key   = (bf16_t*)d_out;         // [4096, 2048]
    bf16_t* xb    = key + NTOK * D_OUT;     // [4096, 2048]

    // --- 1. prep: cvt(x) + 8 weight transposes + bias concat, one launch ---
    TOps tops = {{
        { w_kv, wt_kv, 2048,  512, 16,  16 * 64 },
        { w_q,  wt_q,  2048,  512, 16,  16 * 64 },
        { w_ku, wt_ku,  512, 1024, 32,  32 * 16 },
        { w_kr, wt_kr, 2048, 1024, 32,  32 * 64 },
        { w_vu, wt_vu,  512, 2048, 64,  64 * 16 },
        { w_qu, wt_qu,  512, 1024, 32,  32 * 16 },
        { w_qr, wt_qr,  512, 1024, 32,  32 * 16 },
        { w_o,  wt_o,  2048, 2048, 64,  64 * 64 },
    }};
    int trb = 0;
    for (int i = 0; i < NTOPS; ++i) trb += tops.op[i].nblk;
    prep_kernel<<<CVTB + trb + 1, 256, 0, stream>>>(x, xb, tops, b_kv, b_q, bkvq, trb);

    // --- 2. stage-1 GEMMs: [ckv | qlat] = xb @ [w_kv | w_q] (fused) ---
    // wt_kv/wt_q are contiguous -> single op, N=1024, bias=bkvq.
    GOps<1> s1 = {{
        { xb, wt_kv, bkvq, ckvq, D_IN, D_IN, 0, 1024, 8, 8 * 32 },
    }};
    gemm_multi_kernel<bf16_t, 1><<<8 * 32, 256, 0, stream>>>(s1);

    // --- 3. stage-2 GEMMs: ku, kr, qu, qr, vu (one launch, 1536 blocks) ---
    GOps<5> s2 = {{
        { ckvq,       wt_ku, b_ku, key,   1024,  512,    0, D_OUT,  8, 256 },
        { xb,         wt_kr, b_kr, key,   D_IN, 2048, 1024, D_OUT,  8, 256 },
        { ckvq + 512, wt_qu, b_qu, query, 1024,  512,    0, D_OUT,  8, 256 },
        { ckvq + 512, wt_qr, b_qr, query, 1024,  512, 1024, D_OUT,  8, 256 },
        { ckvq,       wt_vu, b_vu, value, 1024,  512,    0, D_OUT, 16, 512 },
    }};
    gemm_multi_kernel<bf16_t, 5><<<1536, 256, 0, stream>>>(s2);

    // --- 4. flash attention (balanced pairs; in place over query) ---
    attn_mfma_kernel<<<dim3(NQT / 2, NUM_HEAD, BATCH), 256, 0, stream>>>(
        query, key, value);

    // --- 5. out-proj: out = attno @ w_o + b_o (f32) ---
    GOps<1> s3 = {{
        { query, wt_o, b_o, out, D_OUT, 2048, 0, D_OUT, 16, 512 },
    }};
    gemm_multi_kernel<float, 1><<<512, 256, 0, stream>>>(s3);
}

// Round 7
// 431.133 us; speedup vs baseline: 16.3285x; 1.0807x over previous
//
#include <hip/hip_runtime.h>
#include <hip/hip_bf16.h>

typedef __hip_bfloat16 bf16;
typedef __bf16 bf16_t;
typedef __bf16 bf16x8 __attribute__((ext_vector_type(8)));
typedef __bf16 bf16x4v __attribute__((ext_vector_type(4)));
typedef float f32x4 __attribute__((ext_vector_type(4)));

#define D_IN 2048
#define D_OUT 2048
#define DL 512
#define NUM_HEAD 16
#define SEQ 2048
#define HEAD_DIM 128
#define BATCH 2
#define NTOK (BATCH * SEQ) // 4096

__device__ __forceinline__ void stf(float* p, float v) { *p = v; }
__device__ __forceinline__ void stf(bf16_t* p, float v) { *p = (bf16_t)v; }

__device__ __forceinline__ void async_cp16(const bf16_t* g, bf16_t* l) {
    __builtin_amdgcn_global_load_lds(
        (const __attribute__((address_space(1))) void*)g,
        (__attribute__((address_space(3))) void*)l, 16, 0, 0);
}

// ---------------------------------------------------------------------------
// Fused prep kernel (unchanged from R6): x cvt + 8 weight transposes + bias
// concat in one launch.
// ---------------------------------------------------------------------------
#define CVTB 8192          // 4096*2048 / 1024
#define NTOPS 8

struct TOp { const float* W; bf16_t* Wt; int K, N, nx, nblk; };
struct TOps { TOp op[NTOPS]; };

__global__ __launch_bounds__(256) void prep_kernel(
    const float* __restrict__ x, bf16_t* __restrict__ xb,
    TOps ops,
    const float* __restrict__ b_kv, const float* __restrict__ b_q,
    float* __restrict__ bkvq, int trb)
{
    const int tid = threadIdx.x;
    int blk = blockIdx.x;

    if (blk < CVTB) {
        int i = (blk * 256 + tid) * 4;
        float4 v = *(const float4*)&x[i];
        bf16_t o[4] = {(bf16_t)v.x, (bf16_t)v.y, (bf16_t)v.z, (bf16_t)v.w};
        *(ulong1*)&xb[i] = *(ulong1*)o;
        return;
    }
    blk -= CVTB;
    if (blk < trb) {
        int op = 0;
        while (blk >= ops.op[op].nblk) { blk -= ops.op[op].nblk; ++op; }
        const TOp& t = ops.op[op];
        const int n0 = (blk % t.nx) * 32, k0 = (blk / t.nx) * 32;
        __shared__ float tl[32][33];
        const int c = tid & 31, r0 = tid >> 5;
#pragma unroll
        for (int rr = 0; rr < 32; rr += 8)
            tl[r0 + rr][c] = t.W[(size_t)(k0 + r0 + rr) * t.N + n0 + c];
        __syncthreads();
#pragma unroll
        for (int rr = 0; rr < 32; rr += 8)
            t.Wt[(size_t)(n0 + r0 + rr) * t.K + k0 + c] = (bf16_t)tl[c][r0 + rr];
        return;
    }
#pragma unroll
    for (int j = 0; j < 4; ++j) {
        int i = tid + j * 256;
        bkvq[i] = (i < DL) ? b_kv[i] : b_q[i - DL];
    }
}

// ---------------------------------------------------------------------------
// Multi-op MFMA GEMM (unchanged from R6).
// ---------------------------------------------------------------------------
struct GOp { const bf16_t* A; const bf16_t* Wt; const float* bias;
             void* C; int lda, K, col0, ldc, nx, nblk; };
template <int N> struct GOps { GOp op[N]; };

template <typename TC, int NOPS>
__global__ __launch_bounds__(256) void gemm_multi_kernel(GOps<NOPS> ops)
{
    __shared__ __align__(16) bf16_t As[128 * 32];
    __shared__ __align__(16) bf16_t Bs[128 * 32];

    int blk = blockIdx.x;
    int opi = 0;
    while (blk >= ops.op[opi].nblk) { blk -= ops.op[opi].nblk; ++opi; }
    const GOp& g = ops.op[opi];

    const int tid  = threadIdx.x;
    const int wave = tid >> 6, lane = tid & 63;
    const int quad = lane >> 4, l16 = lane & 15;
    const int wm = wave & 1, wn = wave >> 1;
    const int m0 = (blk / g.nx) * 128;
    const int n0 = (blk % g.nx) * 128;

    const int r0 = tid >> 2, c0 = (tid & 3) * 8;
    const bf16_t* Ap0 = g.A  + (size_t)(m0 + r0)      * g.lda + c0;
    const bf16_t* Ap1 = g.A  + (size_t)(m0 + r0 + 64) * g.lda + c0;
    const bf16_t* Bp0 = g.Wt + (size_t)(n0 + r0)      * g.K   + c0;
    const bf16_t* Bp1 = g.Wt + (size_t)(n0 + r0 + 64) * g.K   + c0;

    f32x4 acc[4][4];
#pragma unroll
    for (int i = 0; i < 4; ++i)
#pragma unroll
        for (int j = 0; j < 4; ++j) acc[i][j] = (f32x4){0.f, 0.f, 0.f, 0.f};

    for (int k0 = 0; k0 < g.K; k0 += 32) {
        __syncthreads();
        async_cp16(Ap0 + k0, As + tid * 8);
        async_cp16(Ap1 + k0, As + 2048 + tid * 8);
        async_cp16(Bp0 + k0, Bs + tid * 8);
        async_cp16(Bp1 + k0, Bs + 2048 + tid * 8);
        __syncthreads();

        bf16x8 af[4], bfr[4];
#pragma unroll
        for (int t = 0; t < 4; ++t) {
            af[t]  = *(const bf16x8*)&As[(wm * 64 + t * 16 + l16) * 32 + quad * 8];
            bfr[t] = *(const bf16x8*)&Bs[(wn * 64 + t * 16 + l16) * 32 + quad * 8];
        }
#pragma unroll
        for (int mt = 0; mt < 4; ++mt)
#pragma unroll
            for (int nt = 0; nt < 4; ++nt)
                acc[mt][nt] = __builtin_amdgcn_mfma_f32_16x16x32_bf16(
                    af[mt], bfr[nt], acc[mt][nt], 0, 0, 0);
    }

    TC* C = (TC*)g.C;
    const int mrow = m0 + wm * 64 + quad * 4;
#pragma unroll
    for (int mt = 0; mt < 4; ++mt)
#pragma unroll
        for (int nt = 0; nt < 4; ++nt) {
            int col = n0 + wn * 64 + nt * 16 + l16;
            float bv = g.bias[col];
#pragma unroll
            for (int r = 0; r < 4; ++r)
                stf(&C[(size_t)(mrow + mt * 16 + r) * g.ldc + g.col0 + col],
                    acc[mt][nt][r] + bv);
        }
}

// ---------------------------------------------------------------------------
// MFMA flash attention, round 7:
//  - dual-q: block p computes q-tiles p AND 31-p over ONE k-tile sweep
//    0..31-p (tiles(p) is a prefix of tiles(31-p)) -> 392 vs 528 stagings
//    per (b,h), up to 64 MFMAs/wave per staged tile.
//  - register prefetch: next tile's K/V global loads issued right after the
//    post-staging barrier; vmcnt lands before next iteration's LDS write.
//  - packed V-transpose staging: 8x b64 writes instead of 32x b16.
//  - XCD swizzle: 1-D grid, (b,h) = blk&31 -> all 16 blocks of a (b,h)
//    share blk mod 8 (same XCD under round-robin dispatch) -> K/V L2-resident.
// Output in place over query (each (qt,h,b) owned by exactly one block).
// ---------------------------------------------------------------------------
#define KS_LD 136
#define VT_LD 72
#define P_LD  72
#define NQT   (SEQ / 64) // 32

__global__ __launch_bounds__(256) void attn_mfma_kernel(
    bf16_t* __restrict__ Qg, const bf16_t* __restrict__ Kg,
    const bf16_t* __restrict__ Vg)
{
    __shared__ __align__(16) bf16_t Ks[64 * KS_LD];
    __shared__ __align__(16) bf16_t Vt[128 * VT_LD];
    __shared__ __align__(16) bf16_t Pls[4 * 16 * P_LD];

    const int tid  = threadIdx.x;
    const int wave = tid >> 6;
    const int lane = tid & 63;
    const int quad = lane >> 4;
    const int l16  = lane & 15;

    const int grp = blockIdx.x & 31;
    const int h   = grp & 15;
    const int b   = grp >> 4;
    const int p   = blockIdx.x >> 5;          // 0..15
    const int qtA = p, qtB = NQT - 1 - p;
    const int ntiles = qtB + 1;               // 32 - p

    const int base = b * SEQ;
    const int hd0  = h * HEAD_DIM;
    const float scale = 0.08838834764831845f; // 1/sqrt(128)
    bf16_t* Pw = Pls + wave * 16 * P_LD;

    // Q fragments for both q-tiles (held in registers all kernel)
    bf16x8 qfA[4], qfB[4];
    {
        const bf16_t* qa = Qg + (size_t)(base + qtA * 64 + wave * 16 + l16) * D_OUT + hd0;
        const bf16_t* qb = Qg + (size_t)(base + qtB * 64 + wave * 16 + l16) * D_OUT + hd0;
#pragma unroll
        for (int kb = 0; kb < 4; ++kb) {
            qfA[kb] = *(const bf16x8*)(qa + kb * 32 + quad * 8);
            qfB[kb] = *(const bf16x8*)(qb + kb * 32 + quad * 8);
        }
    }

    f32x4 oA[8], oB[8];
#pragma unroll
    for (int ob = 0; ob < 8; ++ob) {
        oA[ob] = (f32x4){0.f, 0.f, 0.f, 0.f};
        oB[ob] = (f32x4){0.f, 0.f, 0.f, 0.f};
    }
    float mA[4] = {-INFINITY, -INFINITY, -INFINITY, -INFINITY};
    float mB[4] = {-INFINITY, -INFINITY, -INFINITY, -INFINITY};
    float lA[4] = {0.f, 0.f, 0.f, 0.f};
    float lB[4] = {0.f, 0.f, 0.f, 0.f};

    // staging thread mappings
    const int rk = tid >> 4, ck = (tid & 15) * 8;  // K: rows rk+16*jj, 16B col
    const int kg = (tid & 15) * 4, dg = tid >> 4;  // V: keys kg..kg+3, dims dg*8..+7

    bf16x8 kpre[4], vpre[4];
    auto issue = [&](int k0) {
#pragma unroll
        for (int jj = 0; jj < 4; ++jj)
            kpre[jj] = *(const bf16x8*)&Kg[(size_t)(base + k0 + rk + 16 * jj) * D_OUT + hd0 + ck];
#pragma unroll
        for (int kk = 0; kk < 4; ++kk)
            vpre[kk] = *(const bf16x8*)&Vg[(size_t)(base + k0 + kg + kk) * D_OUT + hd0 + dg * 8];
    };
    issue(0);

    auto process = [&](const bf16x8* qf, f32x4* o, float* m_i, float* l_i,
                       int qt, int k0) {
        f32x4 s[4];
#pragma unroll
        for (int nb = 0; nb < 4; ++nb) s[nb] = (f32x4){0.f, 0.f, 0.f, 0.f};
#pragma unroll
        for (int kb = 0; kb < 4; ++kb)
#pragma unroll
            for (int nb = 0; nb < 4; ++nb) {
                bf16x8 bfrag = *(const bf16x8*)&Ks[(nb * 16 + l16) * KS_LD + kb * 32 + quad * 8];
                s[nb] = __builtin_amdgcn_mfma_f32_16x16x32_bf16(qf[kb], bfrag, s[nb], 0, 0, 0);
            }

        const int qrow = qt * 64 + wave * 16 + quad * 4;
#pragma unroll
        for (int nb = 0; nb < 4; ++nb) {
            int key = k0 + nb * 16 + l16;
#pragma unroll
            for (int r = 0; r < 4; ++r) {
                float v = s[nb][r] * scale;
                s[nb][r] = (key <= qrow + r) ? v : -INFINITY;
            }
        }

        float rmax[4];
#pragma unroll
        for (int r = 0; r < 4; ++r)
            rmax[r] = fmaxf(fmaxf(s[0][r], s[1][r]), fmaxf(s[2][r], s[3][r]));
#pragma unroll
        for (int msk = 1; msk < 16; msk <<= 1)
#pragma unroll
            for (int r = 0; r < 4; ++r)
                rmax[r] = fmaxf(rmax[r], __shfl_xor(rmax[r], msk, 64));

        float alpha[4], mnew[4];
#pragma unroll
        for (int r = 0; r < 4; ++r) {
            mnew[r] = fmaxf(m_i[r], rmax[r]);
            alpha[r] = __expf(m_i[r] - mnew[r]); // exp(-inf)=0 first tile
            m_i[r] = mnew[r];
        }

        float rs[4] = {0.f, 0.f, 0.f, 0.f};
#pragma unroll
        for (int nb = 0; nb < 4; ++nb)
#pragma unroll
            for (int r = 0; r < 4; ++r) {
                float pv = __expf(s[nb][r] - mnew[r]);
                s[nb][r] = pv;
                rs[r] += pv;
            }
#pragma unroll
        for (int msk = 1; msk < 16; msk <<= 1)
#pragma unroll
            for (int r = 0; r < 4; ++r)
                rs[r] += __shfl_xor(rs[r], msk, 64);
#pragma unroll
        for (int r = 0; r < 4; ++r)
            l_i[r] = l_i[r] * alpha[r] + rs[r];

#pragma unroll
        for (int ob = 0; ob < 8; ++ob)
#pragma unroll
            for (int r = 0; r < 4; ++r)
                o[ob][r] *= alpha[r];

        // P: C-layout -> wave-private LDS -> A-layout fragments
#pragma unroll
        for (int nb = 0; nb < 4; ++nb)
#pragma unroll
            for (int r = 0; r < 4; ++r)
                Pw[(quad * 4 + r) * P_LD + nb * 16 + l16] = (bf16_t)s[nb][r];
        __builtin_amdgcn_s_waitcnt(0xc07f); // lgkmcnt(0), wave-private region
        bf16x8 pa0 = *(const bf16x8*)&Pw[l16 * P_LD + 0 + quad * 8];
        bf16x8 pa1 = *(const bf16x8*)&Pw[l16 * P_LD + 32 + quad * 8];

#pragma unroll
        for (int ob = 0; ob < 8; ++ob) {
            bf16x8 b0 = *(const bf16x8*)&Vt[(ob * 16 + l16) * VT_LD + 0 + quad * 8];
            o[ob] = __builtin_amdgcn_mfma_f32_16x16x32_bf16(pa0, b0, o[ob], 0, 0, 0);
            bf16x8 b1 = *(const bf16x8*)&Vt[(ob * 16 + l16) * VT_LD + 32 + quad * 8];
            o[ob] = __builtin_amdgcn_mfma_f32_16x16x32_bf16(pa1, b1, o[ob], 0, 0, 0);
        }
    };

    for (int t = 0; t < ntiles; ++t) {
        const int k0 = t * 64;
        __syncthreads(); // prior tile's LDS reads complete
        // write prefetched tile into LDS
#pragma unroll
        for (int jj = 0; jj < 4; ++jj)
            *(bf16x8*)&Ks[(rk + 16 * jj) * KS_LD + ck] = kpre[jj];
#pragma unroll
        for (int j = 0; j < 8; ++j) {
            bf16x4v pk = {vpre[0][j], vpre[1][j], vpre[2][j], vpre[3][j]};
            *(bf16x4v*)&Vt[(dg * 8 + j) * VT_LD + kg] = pk;
        }
        __syncthreads(); // tile visible
        if (t + 1 < ntiles) issue(k0 + 64); // prefetch next (block-uniform)

        process(qfB, oB, mB, lB, qtB, k0);
        if (t <= qtA) process(qfA, oA, mA, lA, qtA, k0);
    }

    // epilogues: O /= l, write over query in place
    auto writeback = [&](f32x4* o, float* l_i, int qt) {
#pragma unroll
        for (int ob = 0; ob < 8; ++ob)
#pragma unroll
            for (int r = 0; r < 4; ++r) {
                int row = qt * 64 + wave * 16 + quad * 4 + r;
                Qg[(size_t)(base + row) * D_OUT + hd0 + ob * 16 + l16] =
                    (bf16_t)(o[ob][r] / l_i[r]);
            }
    };
    writeback(oA, lA, qtA);
    writeback(oB, lB, qtB);
}

extern "C" void kernel_launch(void* const* d_in, const int* in_sizes, int n_in,
                              void* d_out, int out_size, void* d_ws, size_t ws_size,
                              hipStream_t stream)
{
    const float* x    = (const float*)d_in[0];
    const float* w_kv = (const float*)d_in[1];
    const float* b_kv = (const float*)d_in[2];
    const float* w_ku = (const float*)d_in[3];
    const float* b_ku = (const float*)d_in[4];
    const float* w_kr = (const float*)d_in[5];
    const float* b_kr = (const float*)d_in[6];
    const float* w_vu = (const float*)d_in[7];
    const float* b_vu = (const float*)d_in[8];
    const float* w_q  = (const float*)d_in[9];
    const float* b_q  = (const float*)d_in[10];
    const float* w_qu = (const float*)d_in[11];
    const float* b_qu = (const float*)d_in[12];
    const float* w_qr = (const float*)d_in[13];
    const float* b_qr = (const float*)d_in[14];
    const float* w_o  = (const float*)d_in[15];
    const float* b_o  = (const float*)d_in[16];
    float* out = (float*)d_out;

    bf16_t* ws    = (bf16_t*)d_ws;
    bf16_t* ckvq  = ws;                     // [4096, 1024]: ckv | qlat
    bf16_t* query = ckvq  + NTOK * 1024;    // [4096, 2048] -> attn out in place
    bf16_t* value = query + NTOK * D_OUT;   // [4096, 2048]
    bf16_t* wt_kv = value + NTOK * D_OUT;   // [512, 2048]
    bf16_t* wt_q  = wt_kv + 512 * 2048;     // [512, 2048] (contig after wt_kv)
    bf16_t* wt_ku = wt_q  + 512 * 2048;     // [1024, 512]
    bf16_t* wt_kr = wt_ku + 1024 * 512;     // [1024, 2048]
    bf16_t* wt_vu = wt_kr + 1024 * 2048;    // [2048, 512]
    bf16_t* wt_qu = wt_vu + 2048 * 512;     // [1024, 512]
    bf16_t* wt_qr = wt_qu + 1024 * 512;     // [1024, 512]
    bf16_t* wt_o  = wt_qr + 1024 * 512;     // [2048, 2048]
    float*  bkvq  = (float*)(wt_o + 2048 * 2048); // [1024]
    bf16_t* key   = (bf16_t*)d_out;         // [4096, 2048] scratch in d_out
    bf16_t* xb    = key + NTOK * D_OUT;     // [4096, 2048] scratch in d_out

    // --- 1. prep ---
    TOps tops = {{
        { w_kv, wt_kv, 2048,  512, 16,  16 * 64 },
        { w_q,  wt_q,  2048,  512, 16,  16 * 64 },
        { w_ku, wt_ku,  512, 1024, 32,  32 * 16 },
        { w_kr, wt_kr, 2048, 1024, 32,  32 * 64 },
        { w_vu, wt_vu,  512, 2048, 64,  64 * 16 },
        { w_qu, wt_qu,  512, 1024, 32,  32 * 16 },
        { w_qr, wt_qr,  512, 1024, 32,  32 * 16 },
        { w_o,  wt_o,  2048, 2048, 64,  64 * 64 },
    }};
    int trb = 0;
    for (int i = 0; i < NTOPS; ++i) trb += tops.op[i].nblk;
    prep_kernel<<<CVTB + trb + 1, 256, 0, stream>>>(x, xb, tops, b_kv, b_q, bkvq, trb);

    // --- 2. stage-1: [ckv | qlat] = xb @ [w_kv | w_q] ---
    GOps<1> s1 = {{
        { xb, wt_kv, bkvq, ckvq, D_IN, D_IN, 0, 1024, 8, 8 * 32 },
    }};
    gemm_multi_kernel<bf16_t, 1><<<8 * 32, 256, 0, stream>>>(s1);

    // --- 3. stage-2: ku, kr, qu, qr, vu ---
    GOps<5> s2 = {{
        { ckvq,       wt_ku, b_ku, key,   1024,  512,    0, D_OUT,  8, 256 },
        { xb,         wt_kr, b_kr, key,   D_IN, 2048, 1024, D_OUT,  8, 256 },
        { ckvq + 512, wt_qu, b_qu, query, 1024,  512,    0, D_OUT,  8, 256 },
        { ckvq + 512, wt_qr, b_qr, query, 1024,  512, 1024, D_OUT,  8, 256 },
        { ckvq,       wt_vu, b_vu, value, 1024,  512,    0, D_OUT, 16, 512 },
    }};
    gemm_multi_kernel<bf16_t, 5><<<1536, 256, 0, stream>>>(s2);

    // --- 4. flash attention (dual-q, prefetch, XCD swizzle) ---
    attn_mfma_kernel<<<512, 256, 0, stream>>>(query, key, value);

    // --- 5. out-proj ---
    GOps<1> s3 = {{
        { query, wt_o, b_o, out, D_OUT, 2048, 0, D_OUT, 16, 512 },
    }};
    gemm_multi_kernel<float, 1><<<512, 256, 0, stream>>>(s3);
}

// Round 8
// 391.759 us; speedup vs baseline: 17.9696x; 1.1005x over previous
//
#include <hip/hip_runtime.h>
#include <hip/hip_bf16.h>

typedef __hip_bfloat16 bf16;
typedef __bf16 bf16_t;
typedef __bf16 bf16x8 __attribute__((ext_vector_type(8)));
typedef __bf16 bf16x4v __attribute__((ext_vector_type(4)));
typedef float f32x4 __attribute__((ext_vector_type(4)));

#define D_IN 2048
#define D_OUT 2048
#define DL 512
#define NUM_HEAD 16
#define SEQ 2048
#define HEAD_DIM 128
#define BATCH 2
#define NTOK (BATCH * SEQ) // 4096

__device__ __forceinline__ void stf(float* p, float v) { *p = v; }
__device__ __forceinline__ void stf(bf16_t* p, float v) { *p = (bf16_t)v; }

__device__ __forceinline__ void async_cp16(const bf16_t* g, bf16_t* l) {
    __builtin_amdgcn_global_load_lds(
        (const __attribute__((address_space(1))) void*)g,
        (__attribute__((address_space(3))) void*)l, 16, 0, 0);
}

// ---------------------------------------------------------------------------
// Fused prep kernel: x cvt + 8 weight transposes + 2 bias concats.
// ---------------------------------------------------------------------------
#define CVTB 8192          // 4096*2048 / 1024
#define NTOPS 8

struct TOp { const float* W; bf16_t* Wt; int K, N, nx, nblk; };
struct TOps { TOp op[NTOPS]; };

__global__ __launch_bounds__(256) void prep_kernel(
    const float* __restrict__ x, bf16_t* __restrict__ xb,
    TOps ops,
    const float* __restrict__ b_kv, const float* __restrict__ b_q,
    float* __restrict__ bkvq,
    const float* __restrict__ b_qu, const float* __restrict__ b_qr,
    float* __restrict__ bquqr, int trb)
{
    const int tid = threadIdx.x;
    int blk = blockIdx.x;

    if (blk < CVTB) {
        int i = (blk * 256 + tid) * 4;
        float4 v = *(const float4*)&x[i];
        bf16_t o[4] = {(bf16_t)v.x, (bf16_t)v.y, (bf16_t)v.z, (bf16_t)v.w};
        *(ulong1*)&xb[i] = *(ulong1*)o;
        return;
    }
    blk -= CVTB;
    if (blk < trb) {
        int op = 0;
        while (blk >= ops.op[op].nblk) { blk -= ops.op[op].nblk; ++op; }
        const TOp& t = ops.op[op];
        const int n0 = (blk % t.nx) * 32, k0 = (blk / t.nx) * 32;
        __shared__ float tl[32][33];
        const int c = tid & 31, r0 = tid >> 5;
#pragma unroll
        for (int rr = 0; rr < 32; rr += 8)
            tl[r0 + rr][c] = t.W[(size_t)(k0 + r0 + rr) * t.N + n0 + c];
        __syncthreads();
#pragma unroll
        for (int rr = 0; rr < 32; rr += 8)
            t.Wt[(size_t)(n0 + r0 + rr) * t.K + k0 + c] = (bf16_t)tl[c][r0 + rr];
        return;
    }
    blk -= trb;
    if (blk == 0) {
#pragma unroll
        for (int j = 0; j < 4; ++j) {
            int i = tid + j * 256;
            bkvq[i] = (i < DL) ? b_kv[i] : b_q[i - DL];
        }
    } else {
#pragma unroll
        for (int j = 0; j < 8; ++j) {
            int i = tid + j * 256;
            bquqr[i] = (i < 1024) ? b_qu[i] : b_qr[i - 1024];
        }
    }
}

// ---------------------------------------------------------------------------
// Multi-op MFMA GEMM, BK=64 as two 32-col panels (keeps the conflict-free
// BK=32 frag-read pattern AND the linear global_load_lds fill). LDS 32 KiB.
// Per k-tile: 8 async_cp16 + 2 barriers + 32 MFMA/wave.
// ---------------------------------------------------------------------------
struct GOp { const bf16_t* A; const bf16_t* Wt; const float* bias;
             void* C; int lda, K, col0, ldc, nx, nblk; };
template <int N> struct GOps { GOp op[N]; };

template <typename TC, int NOPS>
__global__ __launch_bounds__(256) void gemm_multi_kernel(GOps<NOPS> ops)
{
    __shared__ __align__(16) bf16_t As[2 * 128 * 32]; // 16 KiB
    __shared__ __align__(16) bf16_t Bs[2 * 128 * 32]; // 16 KiB

    int blk = blockIdx.x;
    int opi = 0;
    while (blk >= ops.op[opi].nblk) { blk -= ops.op[opi].nblk; ++opi; }
    const GOp& g = ops.op[opi];

    const int tid  = threadIdx.x;
    const int wave = tid >> 6, lane = tid & 63;
    const int quad = lane >> 4, l16 = lane & 15;
    const int wm = wave & 1, wn = wave >> 1;
    const int m0 = (blk / g.nx) * 128;
    const int n0 = (blk % g.nx) * 128;

    // staging: per call 64 rows x 32 cols; thread: row r0, 16B chunk c0
    const int r0 = tid >> 2, c0 = (tid & 3) * 8;
    const bf16_t* Ap0 = g.A  + (size_t)(m0 + r0)      * g.lda + c0;
    const bf16_t* Ap1 = g.A  + (size_t)(m0 + r0 + 64) * g.lda + c0;
    const bf16_t* Bp0 = g.Wt + (size_t)(n0 + r0)      * g.K   + c0;
    const bf16_t* Bp1 = g.Wt + (size_t)(n0 + r0 + 64) * g.K   + c0;

    f32x4 acc[4][4];
#pragma unroll
    for (int i = 0; i < 4; ++i)
#pragma unroll
        for (int j = 0; j < 4; ++j) acc[i][j] = (f32x4){0.f, 0.f, 0.f, 0.f};

    for (int k0 = 0; k0 < g.K; k0 += 64) {
        __syncthreads();
#pragma unroll
        for (int p = 0; p < 2; ++p) {
            async_cp16(Ap0 + k0 + p * 32, As + p * 4096 + tid * 8);
            async_cp16(Ap1 + k0 + p * 32, As + p * 4096 + 2048 + tid * 8);
            async_cp16(Bp0 + k0 + p * 32, Bs + p * 4096 + tid * 8);
            async_cp16(Bp1 + k0 + p * 32, Bs + p * 4096 + 2048 + tid * 8);
        }
        __syncthreads();

#pragma unroll
        for (int p = 0; p < 2; ++p) {
            bf16x8 af[4], bfr[4];
#pragma unroll
            for (int t = 0; t < 4; ++t) {
                af[t]  = *(const bf16x8*)&As[p * 4096 + (wm * 64 + t * 16 + l16) * 32 + quad * 8];
                bfr[t] = *(const bf16x8*)&Bs[p * 4096 + (wn * 64 + t * 16 + l16) * 32 + quad * 8];
            }
#pragma unroll
            for (int mt = 0; mt < 4; ++mt)
#pragma unroll
                for (int nt = 0; nt < 4; ++nt)
                    acc[mt][nt] = __builtin_amdgcn_mfma_f32_16x16x32_bf16(
                        af[mt], bfr[nt], acc[mt][nt], 0, 0, 0);
        }
    }

    TC* C = (TC*)g.C;
    const int mrow = m0 + wm * 64 + quad * 4;
#pragma unroll
    for (int mt = 0; mt < 4; ++mt)
#pragma unroll
        for (int nt = 0; nt < 4; ++nt) {
            int col = n0 + wn * 64 + nt * 16 + l16;
            float bv = g.bias[col];
#pragma unroll
            for (int r = 0; r < 4; ++r)
                stf(&C[(size_t)(mrow + mt * 16 + r) * g.ldc + g.col0 + col],
                    acc[mt][nt][r] + bv);
        }
}

// ---------------------------------------------------------------------------
// MFMA flash attention, round 8: TRANSPOSED score compute.
//   S^T = K·Q^T via mfma(A=K-rows, B=Q): D col=l16 -> ONE query per lane,
//   rows quad*4+r -> keys. Softmax: in-lane reduce over 16 vals + 2-shuffle
//   butterfly (xor 16/32); m/l/alpha are per-lane scalars.
//   O^T += V^T·P^T: A=V^T (staged transposed, same reads as before),
//   B=P^T from wave-private LDS (packed b64 writes, b128 reads).
// Dual-q + prefetch + XCD swizzle retained from R7.
// ---------------------------------------------------------------------------
#define KS_LD 136
#define VT_LD 72
#define P_LD  72
#define NQT   (SEQ / 64) // 32

__global__ __launch_bounds__(256) void attn_mfma_kernel(
    bf16_t* __restrict__ Qg, const bf16_t* __restrict__ Kg,
    const bf16_t* __restrict__ Vg)
{
    __shared__ __align__(16) bf16_t Ks[64 * KS_LD];
    __shared__ __align__(16) bf16_t Vt[128 * VT_LD];
    __shared__ __align__(16) bf16_t Pls[4 * 16 * P_LD];

    const int tid  = threadIdx.x;
    const int wave = tid >> 6;
    const int lane = tid & 63;
    const int quad = lane >> 4;
    const int l16  = lane & 15;

    const int grp = blockIdx.x & 31;
    const int h   = grp & 15;
    const int b   = grp >> 4;
    const int p   = blockIdx.x >> 5;          // 0..15
    const int qtA = p, qtB = NQT - 1 - p;
    const int ntiles = qtB + 1;               // 32 - p

    const int base = b * SEQ;
    const int hd0  = h * HEAD_DIM;
    const float scale = 0.08838834764831845f; // 1/sqrt(128)
    bf16_t* Pw = Pls + wave * 16 * P_LD;

    // Q fragments for both q-tiles (B-operand: lane n=l16 -> q, k=quad*8+j)
    bf16x8 qfA[4], qfB[4];
    {
        const bf16_t* qa = Qg + (size_t)(base + qtA * 64 + wave * 16 + l16) * D_OUT + hd0;
        const bf16_t* qb = Qg + (size_t)(base + qtB * 64 + wave * 16 + l16) * D_OUT + hd0;
#pragma unroll
        for (int kb = 0; kb < 4; ++kb) {
            qfA[kb] = *(const bf16x8*)(qa + kb * 32 + quad * 8);
            qfB[kb] = *(const bf16x8*)(qb + kb * 32 + quad * 8);
        }
    }

    // O^T accumulators: lane col=l16 -> q, rows -> d = ob*16 + quad*4 + r
    f32x4 oA[8], oB[8];
#pragma unroll
    for (int ob = 0; ob < 8; ++ob) {
        oA[ob] = (f32x4){0.f, 0.f, 0.f, 0.f};
        oB[ob] = (f32x4){0.f, 0.f, 0.f, 0.f};
    }
    float mA = -INFINITY, mB = -INFINITY, lA = 0.f, lB = 0.f;

    // staging thread mappings
    const int rk = tid >> 4, ck = (tid & 15) * 8;  // K staging
    const int kg = (tid & 15) * 4, dg = tid >> 4;  // V-transpose staging

    bf16x8 kpre[4], vpre[4];
    auto issue = [&](int k0) {
#pragma unroll
        for (int jj = 0; jj < 4; ++jj)
            kpre[jj] = *(const bf16x8*)&Kg[(size_t)(base + k0 + rk + 16 * jj) * D_OUT + hd0 + ck];
#pragma unroll
        for (int kk = 0; kk < 4; ++kk)
            vpre[kk] = *(const bf16x8*)&Vg[(size_t)(base + k0 + kg + kk) * D_OUT + hd0 + dg * 8];
    };
    issue(0);

    auto process = [&](const bf16x8* qf, f32x4* o, float& m_i, float& l_i,
                       int qt, int k0) {
        // S^T = K . Q^T : s[nb] holds keys k0+nb*16+quad*4+r for query l16
        f32x4 s[4];
#pragma unroll
        for (int nb = 0; nb < 4; ++nb) s[nb] = (f32x4){0.f, 0.f, 0.f, 0.f};
#pragma unroll
        for (int kb = 0; kb < 4; ++kb)
#pragma unroll
            for (int nb = 0; nb < 4; ++nb) {
                bf16x8 kfrag = *(const bf16x8*)&Ks[(nb * 16 + l16) * KS_LD + kb * 32 + quad * 8];
                s[nb] = __builtin_amdgcn_mfma_f32_16x16x32_bf16(kfrag, qf[kb], s[nb], 0, 0, 0);
            }

        const int qabs = qt * 64 + wave * 16 + l16; // this lane's query row
        if (k0 + 63 <= qt * 64 + wave * 16) {
            // fully-unmasked tile (wave-uniform branch)
#pragma unroll
            for (int nb = 0; nb < 4; ++nb)
#pragma unroll
                for (int r = 0; r < 4; ++r) s[nb][r] *= scale;
        } else {
#pragma unroll
            for (int nb = 0; nb < 4; ++nb) {
                int key = k0 + nb * 16 + quad * 4;
#pragma unroll
                for (int r = 0; r < 4; ++r)
                    s[nb][r] = (key + r <= qabs) ? s[nb][r] * scale : -INFINITY;
            }
        }

        // row (=query) max: in-lane over 16, butterfly across quads
        float rmax = -INFINITY;
#pragma unroll
        for (int nb = 0; nb < 4; ++nb)
#pragma unroll
            for (int r = 0; r < 4; ++r) rmax = fmaxf(rmax, s[nb][r]);
        rmax = fmaxf(rmax, __shfl_xor(rmax, 16, 64));
        rmax = fmaxf(rmax, __shfl_xor(rmax, 32, 64));

        const float mnew = fmaxf(m_i, rmax);
        const float alpha = __expf(m_i - mnew); // exp(-inf)=0 first tile
        m_i = mnew;

        float rs = 0.f;
#pragma unroll
        for (int nb = 0; nb < 4; ++nb)
#pragma unroll
            for (int r = 0; r < 4; ++r) {
                float pv = __expf(s[nb][r] - mnew);
                s[nb][r] = pv;
                rs += pv;
            }
        rs += __shfl_xor(rs, 16, 64);
        rs += __shfl_xor(rs, 32, 64);
        l_i = l_i * alpha + rs;

#pragma unroll
        for (int ob = 0; ob < 8; ++ob)
#pragma unroll
            for (int r = 0; r < 4; ++r) o[ob][r] *= alpha;

        // P^T -> wave-private LDS: row q=l16, keys nb*16+quad*4..+3 (b64 packed)
#pragma unroll
        for (int nb = 0; nb < 4; ++nb) {
            bf16x4v pk = {(bf16_t)s[nb][0], (bf16_t)s[nb][1],
                          (bf16_t)s[nb][2], (bf16_t)s[nb][3]};
            *(bf16x4v*)&Pw[l16 * P_LD + nb * 16 + quad * 4] = pk;
        }
        __builtin_amdgcn_s_waitcnt(0xc07f); // lgkmcnt(0), wave-private region
        bf16x8 pb0 = *(const bf16x8*)&Pw[l16 * P_LD + 0 + quad * 8];
        bf16x8 pb1 = *(const bf16x8*)&Pw[l16 * P_LD + 32 + quad * 8];

        // O^T += V^T . P^T (A = V^T staged transposed, B = P^T)
#pragma unroll
        for (int ob = 0; ob < 8; ++ob) {
            bf16x8 v0 = *(const bf16x8*)&Vt[(ob * 16 + l16) * VT_LD + 0 + quad * 8];
            o[ob] = __builtin_amdgcn_mfma_f32_16x16x32_bf16(v0, pb0, o[ob], 0, 0, 0);
            bf16x8 v1 = *(const bf16x8*)&Vt[(ob * 16 + l16) * VT_LD + 32 + quad * 8];
            o[ob] = __builtin_amdgcn_mfma_f32_16x16x32_bf16(v1, pb1, o[ob], 0, 0, 0);
        }
    };

    for (int t = 0; t < ntiles; ++t) {
        const int k0 = t * 64;
        __syncthreads(); // prior tile's LDS reads complete
#pragma unroll
        for (int jj = 0; jj < 4; ++jj)
            *(bf16x8*)&Ks[(rk + 16 * jj) * KS_LD + ck] = kpre[jj];
#pragma unroll
        for (int j = 0; j < 8; ++j) {
            bf16x4v pk = {vpre[0][j], vpre[1][j], vpre[2][j], vpre[3][j]};
            *(bf16x4v*)&Vt[(dg * 8 + j) * VT_LD + kg] = pk;
        }
        __syncthreads(); // tile visible
        if (t + 1 < ntiles) issue(k0 + 64); // prefetch next (block-uniform)

        process(qfB, oB, mB, lB, qtB, k0);
        if (t <= qtA) process(qfA, oA, mA, lA, qtA, k0);
    }

    // epilogue: per lane ONE query row q, 8x b64 packed stores
    auto writeback = [&](f32x4* o, float l_i, int qt) {
        const int q = qt * 64 + wave * 16 + l16;
        const float inv = 1.f / l_i;
        bf16_t* orow = Qg + (size_t)(base + q) * D_OUT + hd0;
#pragma unroll
        for (int ob = 0; ob < 8; ++ob) {
            bf16x4v pk = {(bf16_t)(o[ob][0] * inv), (bf16_t)(o[ob][1] * inv),
                          (bf16_t)(o[ob][2] * inv), (bf16_t)(o[ob][3] * inv)};
            *(bf16x4v*)&orow[ob * 16 + quad * 4] = pk;
        }
    };
    writeback(oA, lA, qtA);
    writeback(oB, lB, qtB);
}

extern "C" void kernel_launch(void* const* d_in, const int* in_sizes, int n_in,
                              void* d_out, int out_size, void* d_ws, size_t ws_size,
                              hipStream_t stream)
{
    const float* x    = (const float*)d_in[0];
    const float* w_kv = (const float*)d_in[1];
    const float* b_kv = (const float*)d_in[2];
    const float* w_ku = (const float*)d_in[3];
    const float* b_ku = (const float*)d_in[4];
    const float* w_kr = (const float*)d_in[5];
    const float* b_kr = (const float*)d_in[6];
    const float* w_vu = (const float*)d_in[7];
    const float* b_vu = (const float*)d_in[8];
    const float* w_q  = (const float*)d_in[9];
    const float* b_q  = (const float*)d_in[10];
    const float* w_qu = (const float*)d_in[11];
    const float* b_qu = (const float*)d_in[12];
    const float* w_qr = (const float*)d_in[13];
    const float* b_qr = (const float*)d_in[14];
    const float* w_o  = (const float*)d_in[15];
    const float* b_o  = (const float*)d_in[16];
    float* out = (float*)d_out;

    bf16_t* ws    = (bf16_t*)d_ws;
    bf16_t* ckvq  = ws;                     // [4096, 1024]: ckv | qlat
    bf16_t* query = ckvq  + NTOK * 1024;    // [4096, 2048] -> attn out in place
    bf16_t* value = query + NTOK * D_OUT;   // [4096, 2048]
    bf16_t* wt_kv = value + NTOK * D_OUT;   // [512, 2048]
    bf16_t* wt_q  = wt_kv + 512 * 2048;     // [512, 2048] (contig after wt_kv)
    bf16_t* wt_ku = wt_q  + 512 * 2048;     // [1024, 512]
    bf16_t* wt_kr = wt_ku + 1024 * 512;     // [1024, 2048]
    bf16_t* wt_vu = wt_kr + 1024 * 2048;    // [2048, 512]
    bf16_t* wt_qu = wt_vu + 2048 * 512;     // [1024, 512]
    bf16_t* wt_qr = wt_qu + 1024 * 512;     // [1024, 512] (contig: quqr [2048,512])
    bf16_t* wt_o  = wt_qr + 1024 * 512;     // [2048, 2048]
    float*  bkvq  = (float*)(wt_o + 2048 * 2048);  // [1024]
    float*  bquqr = bkvq + 1024;                   // [2048]
    bf16_t* key   = (bf16_t*)d_out;         // [4096, 2048] scratch in d_out
    bf16_t* xb    = key + NTOK * D_OUT;     // [4096, 2048] scratch in d_out

    // --- 1. prep ---
    TOps tops = {{
        { w_kv, wt_kv, 2048,  512, 16,  16 * 64 },
        { w_q,  wt_q,  2048,  512, 16,  16 * 64 },
        { w_ku, wt_ku,  512, 1024, 32,  32 * 16 },
        { w_kr, wt_kr, 2048, 1024, 32,  32 * 64 },
        { w_vu, wt_vu,  512, 2048, 64,  64 * 16 },
        { w_qu, wt_qu,  512, 1024, 32,  32 * 16 },
        { w_qr, wt_qr,  512, 1024, 32,  32 * 16 },
        { w_o,  wt_o,  2048, 2048, 64,  64 * 64 },
    }};
    int trb = 0;
    for (int i = 0; i < NTOPS; ++i) trb += tops.op[i].nblk;
    prep_kernel<<<CVTB + trb + 2, 256, 0, stream>>>(
        x, xb, tops, b_kv, b_q, bkvq, b_qu, b_qr, bquqr, trb);

    // --- 2. stage-1: [ckv | qlat] = xb @ [w_kv | w_q] ---
    GOps<1> s1 = {{
        { xb, wt_kv, bkvq, ckvq, D_IN, D_IN, 0, 1024, 8, 8 * 32 },
    }};
    gemm_multi_kernel<bf16_t, 1><<<8 * 32, 256, 0, stream>>>(s1);

    // --- 3. stage-2: kr (longest first), quqr (merged), vu, ku ---
    GOps<4> s2 = {{
        { xb,         wt_kr, b_kr,  key,   D_IN, 2048, 1024, D_OUT,  8, 256 },
        { ckvq + 512, wt_qu, bquqr, query, 1024,  512,    0, D_OUT, 16, 512 },
        { ckvq,       wt_vu, b_vu,  value, 1024,  512,    0, D_OUT, 16, 512 },
        { ckvq,       wt_ku, b_ku,  key,   1024,  512,    0, D_OUT,  8, 256 },
    }};
    gemm_multi_kernel<bf16_t, 4><<<1536, 256, 0, stream>>>(s2);

    // --- 4. flash attention (S^T form, dual-q, prefetch, XCD swizzle) ---
    attn_mfma_kernel<<<512, 256, 0, stream>>>(query, key, value);

    // --- 5. out-proj ---
    GOps<1> s3 = {{
        { query, wt_o, b_o, out, D_OUT, 2048, 0, D_OUT, 16, 512 },
    }};
    gemm_multi_kernel<float, 1><<<512, 256, 0, stream>>>(s3);
}